// Round 12
// baseline (771.101 us; speedup 1.0000x reference)
//
#include <hip/hip_runtime.h>
#include <math.h>

#define D_MODEL 512
#define NHEAD   8
#define DKH     64
#define NLAYER  6
#define FFDIM   2048
#define VOCAB   512
#define BB      4
#define SS      1024
#define NROWS   4096

typedef unsigned short ushort_t;
typedef short short8 __attribute__((ext_vector_type(8)));
typedef float f32x4  __attribute__((ext_vector_type(4)));

__device__ __forceinline__ float bf2f(ushort_t u) {
    union { float f; unsigned int i; } x; x.i = ((unsigned int)u) << 16; return x.f;
}
__device__ __forceinline__ ushort_t f2bf(float f) {
    union { float f; unsigned int i; } x; x.f = f;
    unsigned int r = x.i + 0x7FFFu + ((x.i >> 16) & 1u);
    return (ushort_t)(r >> 16);
}
__device__ __forceinline__ void gload_lds16(const void* g, void* l) {
    __builtin_amdgcn_global_load_lds(
        (const __attribute__((address_space(1))) void*)g,
        (__attribute__((address_space(3))) void*)l, 16, 0, 0);
}

// ------------------------------------------------------------- weight convert
// One-shot: all 6 layers in a single dispatch (18432 blocks).
// Per-layer layout: qkv 786432 | wo 262144 | w1 1048576 | w2 1048576
__global__ __launch_bounds__(256) void cvt_all(
    const float* __restrict__ wq, const float* __restrict__ wk, const float* __restrict__ wv,
    const float* __restrict__ wo, const float* __restrict__ w1, const float* __restrict__ w2,
    const float* __restrict__ bq, const float* __restrict__ bk, const float* __restrict__ bv,
    ushort_t* __restrict__ wl, float* __restrict__ bqkv)
{
    int idx = blockIdx.x * 256 + threadIdx.x;   // quad id, 4,718,592 total
    int e = idx * 4;
    int l = e / 3145728;
    int off = e - l * 3145728;
    float4 v;
    if (off < 786432) {
        if (off < 262144)       v = *(const float4*)(wq + l * 262144 + off);
        else if (off < 524288)  v = *(const float4*)(wk + l * 262144 + (off - 262144));
        else                    v = *(const float4*)(wv + l * 262144 + (off - 524288));
    } else if (off < 1048576)   v = *(const float4*)(wo + l * 262144 + (off - 786432));
    else if (off < 2097152)     v = *(const float4*)(w1 + l * 1048576 + (off - 1048576));
    else                        v = *(const float4*)(w2 + l * 1048576 + (off - 2097152));
    union { ushort_t u[4]; uint2 q; } pk;
    pk.u[0] = f2bf(v.x); pk.u[1] = f2bf(v.y); pk.u[2] = f2bf(v.z); pk.u[3] = f2bf(v.w);
    *(uint2*)(wl + e) = pk.q;
    if (idx < 2304) {           // 6 layers x 1536 qkv-bias floats
        int b4 = idx * 4;
        int bl = b4 / 1536;
        int r  = b4 - bl * 1536;
        float4 bv4;
        if (r < 512)       bv4 = *(const float4*)(bq + bl * 512 + r);
        else if (r < 1024) bv4 = *(const float4*)(bk + bl * 512 + (r - 512));
        else               bv4 = *(const float4*)(bv + bl * 512 + (r - 1024));
        *(float4*)(bqkv + b4) = bv4;
    }
}

// Per-layer fallback (if ws too small for one-shot)
__global__ __launch_bounds__(256) void cvt_layer(
    const float* __restrict__ wq, const float* __restrict__ wk, const float* __restrict__ wv,
    const float* __restrict__ wo, const float* __restrict__ w1, const float* __restrict__ w2,
    const float* __restrict__ bq, const float* __restrict__ bk, const float* __restrict__ bv,
    ushort_t* __restrict__ wl, float* __restrict__ bqkv)
{
    int idx = blockIdx.x * 256 + threadIdx.x;
    int e = idx * 4;
    float4 v;
    if (e < 786432) {
        if (e < 262144)       v = *(const float4*)(wq + e);
        else if (e < 524288)  v = *(const float4*)(wk + (e - 262144));
        else                  v = *(const float4*)(wv + (e - 524288));
    } else if (e < 1048576)   v = *(const float4*)(wo + (e - 786432));
    else if (e < 2097152)     v = *(const float4*)(w1 + (e - 1048576));
    else                      v = *(const float4*)(w2 + (e - 2097152));
    union { ushort_t u[4]; uint2 q; } pk;
    pk.u[0] = f2bf(v.x); pk.u[1] = f2bf(v.y); pk.u[2] = f2bf(v.z); pk.u[3] = f2bf(v.w);
    *(uint2*)(wl + e) = pk.q;
    if (idx < 384) {
        int b4 = idx * 4;
        float4 bv4;
        if (b4 < 512)       bv4 = *(const float4*)(bq + b4);
        else if (b4 < 1024) bv4 = *(const float4*)(bk + (b4 - 512));
        else                bv4 = *(const float4*)(bv + (b4 - 1024));
        *(float4*)(bqkv + b4) = bv4;
    }
}

__global__ __launch_bounds__(256) void cvt_simple(
    const float* __restrict__ src, ushort_t* __restrict__ dst)
{
    int e = (blockIdx.x * 256 + threadIdx.x) * 4;
    float4 v = *(const float4*)(src + e);
    union { ushort_t u[4]; uint2 q; } pk;
    pk.u[0] = f2bf(v.x); pk.u[1] = f2bf(v.y); pk.u[2] = f2bf(v.z); pk.u[3] = f2bf(v.w);
    *(uint2*)(dst + e) = pk.q;
}

__global__ __launch_bounds__(256) void maskbias_kernel(
    const int* __restrict__ am, float* __restrict__ mb)
{
    int i = blockIdx.x * 256 + threadIdx.x;
    if (i < NROWS) mb[i] = am[i] ? 0.f : -1e9f;
}

// ---------------------------------------------------------------- embedding
__global__ __launch_bounds__(512) void embed_kernel(
    const int* __restrict__ ids, const float* __restrict__ emb,
    float* __restrict__ xf, ushort_t* __restrict__ xb)
{
    int row = blockIdx.x;
    int d   = threadIdx.x;
    int s   = row & (SS - 1);
    int tok = ids[row];
    float div = expf(-(float)(d & ~1) * 0.0179889460390586f);
    float arg = (float)s * div;
    float pe  = (d & 1) ? cosf(arg) : sinf(arg);
    float v = emb[(size_t)tok * D_MODEL + d] * 22.62741699796952f + pe;
    xf[(size_t)row * D_MODEL + d] = v;
    xb[(size_t)row * D_MODEL + d] = f2bf(v);
}

// ---------------------------------------------------------------- layernorm
__global__ __launch_bounds__(512) void ln_kernel(
    const float* __restrict__ x, const float* __restrict__ g,
    const float* __restrict__ b, float* __restrict__ outf, ushort_t* __restrict__ outb)
{
    int row = blockIdx.x;
    int d   = threadIdx.x;
    int wave = d >> 6, lane = d & 63;
    __shared__ float red[8];

    float v = x[(size_t)row * D_MODEL + d];
    float s = v;
#pragma unroll
    for (int o = 32; o > 0; o >>= 1) s += __shfl_xor(s, o);
    if (lane == 0) red[wave] = s;
    __syncthreads();
    float tot = 0.f;
#pragma unroll
    for (int i = 0; i < 8; ++i) tot += red[i];
    float mu = tot * (1.0f / D_MODEL);
    float c  = v - mu;
    __syncthreads();
    float s2 = c * c;
#pragma unroll
    for (int o = 32; o > 0; o >>= 1) s2 += __shfl_xor(s2, o);
    if (lane == 0) red[wave] = s2;
    __syncthreads();
    float tot2 = 0.f;
#pragma unroll
    for (int i = 0; i < 8; ++i) tot2 += red[i];
    float var = tot2 * (1.0f / D_MODEL);
    float y = c * (1.0f / sqrtf(var + 1e-5f)) * g[d] + b[d];
    outf[(size_t)row * D_MODEL + d] = y;
    outb[(size_t)row * D_MODEL + d] = f2bf(y);
}

// ---------------------------------------------------------------- MFMA GEMM
// R9 single-buffer structure + T1 XCD-chunked block swizzle. BK=64, XOR
// source-swizzled LDS. Grid sizes are multiples of 8 (bijective swizzle).
// 128x128 tiles for wide GEMMs (m93: 2.7x per-FLOP efficiency of 64 tiles).
template<int BM, int BN, bool RELU, bool RES, bool OBF16, bool VT>
__global__ __launch_bounds__(256) void gemm_kernel(
    const ushort_t* __restrict__ A, const ushort_t* __restrict__ W,
    const float* __restrict__ bias, const float* __restrict__ res,
    void* __restrict__ out, ushort_t* __restrict__ vtg, int M, int N, int K)
{
    constexpr int WMT = BM / 2, WNT = BN / 2;
    constexpr int FM = WMT / 16, FN = WNT / 16;
    constexpr int ISSA = BM / 32, ISSB = BN / 32;
    __shared__ ushort_t As[BM * 64];
    __shared__ ushort_t Bs[BN * 64];

    const int t = threadIdx.x;
    const int w = t >> 6, lane = t & 63;
    const int wr = w >> 1, wc = w & 1;

    // XCD-chunked swizzle (nwg % 8 == 0 for all our launches)
    const int nwg  = gridDim.x * gridDim.y;
    const int bidl = blockIdx.y * gridDim.x + blockIdx.x;
    const int chunk = nwg >> 3;
    const int wg = (bidl & 7) * chunk + (bidl >> 3);
    const int col0 = (wg % gridDim.x) * BN;
    const int row0 = (wg / gridDim.x) * BM;

    const int lrow = lane & 15, kg = lane >> 4;
    const int srow = t >> 3;                       // 0..31
    const int sk8  = (t & 7) ^ ((t >> 3) & 7);     // pre-swizzled source k8

    f32x4 acc[FM][FN];
#pragma unroll
    for (int m = 0; m < FM; ++m)
#pragma unroll
        for (int n = 0; n < FN; ++n) acc[m][n] = (f32x4){0.f, 0.f, 0.f, 0.f};

    for (int k0 = 0; k0 < K; k0 += 64) {
#pragma unroll
        for (int i = 0; i < ISSA; ++i)
            gload_lds16(A + (size_t)(row0 + i * 32 + srow) * K + k0 + sk8 * 8,
                        (char*)As + i * 4096 + t * 16);
#pragma unroll
        for (int i = 0; i < ISSB; ++i)
            gload_lds16(W + (size_t)(col0 + i * 32 + srow) * K + k0 + sk8 * 8,
                        (char*)Bs + i * 4096 + t * 16);
        __syncthreads();
#pragma unroll
        for (int kk = 0; kk < 2; ++kk) {
            short8 af[FM], bfv[FN];
#pragma unroll
            for (int m = 0; m < FM; ++m) {
                const int row = wr * WMT + m * 16 + lrow;
                af[m] = *(const short8*)&As[row * 64 + (((kk * 4 + kg) ^ (lrow & 7)) << 3)];
            }
#pragma unroll
            for (int n = 0; n < FN; ++n) {
                const int col = wc * WNT + n * 16 + lrow;
                bfv[n] = *(const short8*)&Bs[col * 64 + (((kk * 4 + kg) ^ (lrow & 7)) << 3)];
            }
#pragma unroll
            for (int m = 0; m < FM; ++m)
#pragma unroll
                for (int n = 0; n < FN; ++n)
                    acc[m][n] = __builtin_amdgcn_mfma_f32_16x16x32_bf16(
                        af[m], bfv[n], acc[m][n], 0, 0, 0);
        }
        __syncthreads();
    }

    const int lrow4 = (lane >> 4) * 4;
    const int lcol  = lane & 15;
#pragma unroll
    for (int m = 0; m < FM; ++m)
#pragma unroll
        for (int n = 0; n < FN; ++n) {
            const int col = col0 + wc * WNT + n * 16 + lcol;
            const float bv = bias ? bias[col] : 0.f;
            const int row_base = row0 + wr * WMT + m * 16 + lrow4;
            if (VT && col >= 1024) {
                const int vh = (col - 1024) >> 6;
                const int vd = (col - 1024) & 63;
                const int bq = row_base >> 10;
                const int s0 = row_base & 1023;
                union { ushort_t u[4]; uint2 q; } pk;
#pragma unroll
                for (int j = 0; j < 4; ++j) pk.u[j] = f2bf(acc[m][n][j] + bv);
                *(uint2*)(vtg + ((size_t)(bq * 8 + vh) * 64 + vd) * 1024 + s0) = pk.q;
            } else {
#pragma unroll
                for (int j = 0; j < 4; ++j) {
                    const int row = row_base + j;
                    float v = acc[m][n][j] + bv;
                    if (RES)  v += res[(size_t)row * N + col];
                    if (RELU) v = fmaxf(v, 0.f);
                    if (OBF16) ((ushort_t*)out)[(size_t)row * N + col] = f2bf(v);
                    else       ((float*)out)[(size_t)row * N + col] = v;
                }
            }
        }
}

// ---------------------------------------------------------------- attention
// R9 exact structure (no setprio — barrier-synced lockstep loop is m190's
// regime where setprio HURTS). Swapped-operand MFMA flash attention,
// zero-transport P handoff, LDS-staged double-buffered K/V tiles.
// K swizzle f(row)=(row>>3)&7; V swizzle f(row)=row&7.
__global__ __launch_bounds__(256) void attn_kernel(
    const ushort_t* __restrict__ qkv, const ushort_t* __restrict__ vtg,
    const float* __restrict__ mbias, ushort_t* __restrict__ o)
{
    __shared__ ushort_t Kl[2][64 * 64];   // [key][d]
    __shared__ ushort_t Vl[2][64 * 64];   // [d][key]

    const int t = threadIdx.x, w = t >> 6, l = t & 63;
    const int bid = blockIdx.x;
    const int qt = 15 - (bid >> 5);        // heavy tiles first
    const int bh = bid & 31, b = bh >> 3, h = bh & 7;
    const int q0 = qt * 64;
    const int lg = l >> 4, lr = l & 15;
    const int qi = q0 + w * 16 + lr;       // this lane's query

    const ushort_t* qrow = qkv + (size_t)(b * SS + qi) * 1536 + h * 64;
    const short8 qa0 = *(const short8*)(qrow + lg * 8);
    const short8 qa1 = *(const short8*)(qrow + 32 + lg * 8);

    float m_run = -1e30f, l_run = 0.f;
    f32x4 oacc[4];
#pragma unroll
    for (int nb = 0; nb < 4; ++nb) oacc[nb] = (f32x4){0.f, 0.f, 0.f, 0.f};

    const int krow = 32 * ((lr >> 1) & 1) + 8 * (lr >> 2) + (lr & 1);
    const ushort_t* qkvK = qkv + (size_t)(b * SS) * 1536 + 512 + h * 64;
    const ushort_t* vtgB = vtg + (size_t)bh * 64 * 1024;
    const float*    mb0  = mbias + b * SS + 8 * lg;

    const int sr0 = t >> 3, sc0 = t & 7;

    auto STAGE = [&](int buf, int kt) {
#pragma unroll
        for (int p = 0; p < 2; ++p) {
            const int row = p * 32 + sr0;
            const int ch  = sc0 ^ ((row >> 3) & 7);                 // K swizzle
            gload_lds16(qkvK + (size_t)(kt * 64 + row) * 1536 + ch * 8,
                        (char*)&Kl[buf][0] + (p * 256 + t) * 16);
        }
#pragma unroll
        for (int p = 0; p < 2; ++p) {
            const int row = p * 32 + sr0;
            const int ch  = sc0 ^ (row & 7);                        // V swizzle
            gload_lds16(vtgB + (size_t)row * 1024 + kt * 64 + ch * 8,
                        (char*)&Vl[buf][0] + (p * 256 + t) * 16);
        }
    };

    auto COMPUTE = [&](int buf, int kt) {
        const ushort_t* Kb = &Kl[buf][0];
        const ushort_t* Vb = &Vl[buf][0];
        short8 kf[8], vf[8];
#pragma unroll
        for (int nf = 0; nf < 4; ++nf) {
            const int row = 2 * nf + krow;
            const int sw  = (row >> 3) & 7;
            kf[2 * nf]     = *(const short8*)&Kb[row * 64 + ((lg ^ sw) << 3)];
            kf[2 * nf + 1] = *(const short8*)&Kb[row * 64 + (((4 + lg) ^ sw) << 3)];
        }
#pragma unroll
        for (int nb = 0; nb < 4; ++nb) {
            const int row = 16 * nb + lr;
            const int sw  = row & 7;
            vf[2 * nb]     = *(const short8*)&Vb[row * 64 + ((lg ^ sw) << 3)];
            vf[2 * nb + 1] = *(const short8*)&Vb[row * 64 + (((4 + lg) ^ sw) << 3)];
        }
        const float* mrow = mb0 + kt * 64;
        const float4 mA = *(const float4*)(mrow);
        const float4 mB = *(const float4*)(mrow + 4);
        const float4 mC = *(const float4*)(mrow + 32);
        const float4 mD = *(const float4*)(mrow + 36);
        // S = K * Q^T
        f32x4 s[4];
#pragma unroll
        for (int nf = 0; nf < 4; ++nf) {
            f32x4 a = (f32x4){0.f, 0.f, 0.f, 0.f};
            a = __builtin_amdgcn_mfma_f32_16x16x32_bf16(kf[2 * nf],     qa0, a, 0, 0, 0);
            a = __builtin_amdgcn_mfma_f32_16x16x32_bf16(kf[2 * nf + 1], qa1, a, 0, 0, 0);
            s[nf] = a;
        }
        const bool diag = (kt == qt);
        const int kbase = kt * 64 + 8 * lg;
#pragma unroll
        for (int nf = 0; nf < 4; ++nf) {
#pragma unroll
            for (int r = 0; r < 4; ++r) {
                const int e = r & 1, oo = (r >> 1) & 1;
                const int idx = 2 * nf + e;              // 0..7
                const float bias = oo ? (idx < 4 ? ((const float*)&mC)[idx] : ((const float*)&mD)[idx - 4])
                                      : (idx < 4 ? ((const float*)&mA)[idx] : ((const float*)&mB)[idx - 4]);
                float sv = s[nf][r] * 0.125f + bias;
                if (diag && (kbase + idx + 32 * oo) > qi) sv = -1e9f;
                s[nf][r] = sv;
            }
        }
        float pm[4];
#pragma unroll
        for (int nf = 0; nf < 4; ++nf)
            pm[nf] = fmaxf(fmaxf(s[nf][0], s[nf][1]), fmaxf(s[nf][2], s[nf][3]));
        float mx = fmaxf(fmaxf(pm[0], pm[1]), fmaxf(pm[2], pm[3]));
        mx = fmaxf(mx, __shfl_xor(mx, 16));
        mx = fmaxf(mx, __shfl_xor(mx, 32));
        const float mnew = fmaxf(m_run, mx);
        const float rs   = __expf(m_run - mnew);
        m_run = mnew;
        float ps[4];
#pragma unroll
        for (int nf = 0; nf < 4; ++nf) {
#pragma unroll
            for (int r = 0; r < 4; ++r) s[nf][r] = __expf(s[nf][r] - mnew);
            ps[nf] = (s[nf][0] + s[nf][1]) + (s[nf][2] + s[nf][3]);
        }
        float tsum = (ps[0] + ps[1]) + (ps[2] + ps[3]);
        tsum += __shfl_xor(tsum, 16);
        tsum += __shfl_xor(tsum, 32);
        l_run = l_run * rs + tsum;
#pragma unroll
        for (int nb = 0; nb < 4; ++nb)
#pragma unroll
            for (int r = 0; r < 4; ++r) oacc[nb][r] *= rs;
        union { unsigned u[4]; short8 s8; } pa0u, pa1u;
#pragma unroll
        for (int nf = 0; nf < 4; ++nf) {
            pa0u.u[nf] = ((unsigned)f2bf(s[nf][1]) << 16) | (unsigned)f2bf(s[nf][0]);
            pa1u.u[nf] = ((unsigned)f2bf(s[nf][3]) << 16) | (unsigned)f2bf(s[nf][2]);
        }
#pragma unroll
        for (int nb = 0; nb < 4; ++nb) {
            oacc[nb] = __builtin_amdgcn_mfma_f32_16x16x32_bf16(vf[2 * nb],     pa0u.s8, oacc[nb], 0, 0, 0);
            oacc[nb] = __builtin_amdgcn_mfma_f32_16x16x32_bf16(vf[2 * nb + 1], pa1u.s8, oacc[nb], 0, 0, 0);
        }
    };

    STAGE(0, 0);
    asm volatile("s_waitcnt vmcnt(0)" ::: "memory");
    __syncthreads();
    int buf = 0;
    for (int kt = 0; kt <= qt; ++kt) {
        if (kt < qt) STAGE(buf ^ 1, kt + 1);   // issue next tile before compute
        COMPUTE(buf, kt);
        asm volatile("s_waitcnt vmcnt(0)" ::: "memory");
        __syncthreads();
        buf ^= 1;
    }

    const float inv = 1.0f / l_run;
    ushort_t* orow = o + (size_t)(b * SS + qi) * 512 + h * 64;
#pragma unroll
    for (int nb = 0; nb < 4; ++nb) {
        union { ushort_t u[4]; uint2 q; } pk;
#pragma unroll
        for (int r = 0; r < 4; ++r) pk.u[r] = f2bf(oacc[nb][r] * inv);
        *(uint2*)(orow + nb * 16 + 4 * lg) = pk.q;
    }
}

// ---------------------------------------------------------------- launch
extern "C" void kernel_launch(void* const* d_in, const int* in_sizes, int n_in,
                              void* d_out, int out_size, void* d_ws, size_t ws_size,
                              hipStream_t stream)
{
    const int*   ids   = (const int*)d_in[0];
    const int*   am    = (const int*)d_in[1];
    const float* emb   = (const float*)d_in[2];
    const float* wq    = (const float*)d_in[3];
    const float* bq    = (const float*)d_in[4];
    const float* wk    = (const float*)d_in[5];
    const float* bk    = (const float*)d_in[6];
    const float* wv    = (const float*)d_in[7];
    const float* bv    = (const float*)d_in[8];
    const float* wo    = (const float*)d_in[9];
    const float* bo    = (const float*)d_in[10];
    const float* ln1g  = (const float*)d_in[11];
    const float* ln1b  = (const float*)d_in[12];
    const float* w1    = (const float*)d_in[13];
    const float* b1    = (const float*)d_in[14];
    const float* w2    = (const float*)d_in[15];
    const float* b2    = (const float*)d_in[16];
    const float* ln2g  = (const float*)d_in[17];
    const float* ln2b  = (const float*)d_in[18];
    const float* lnfg  = (const float*)d_in[19];
    const float* lnfb  = (const float*)d_in[20];
    const float* lmw   = (const float*)d_in[21];

    char* base = (char*)d_ws;
    float*    h    = (float*)(base);                    //  8 MB
    float*    h2   = (float*)(base + 8388608);          //  8 MB (attn: vtg 4MB)
    ushort_t* hb   = (ushort_t*)(base + 16777216);      //  4 MB
    ushort_t* act  = (ushort_t*)(base + 20971520);      // 16 MB shared
    ushort_t* qkvb = act;                               //   12 MB
    ushort_t* ob   = act + 6291456;                     //    4 MB
    ushort_t* fbuf = act;                               //   16 MB (after attn phase)
    ushort_t* vtg  = (ushort_t*)h2;                     //    4 MB, attn-phase only

    // weight-conversion scratch: one-shot if ws allows, else per-layer rotate
    const bool onep = ws_size >= (size_t)76100000;
    ushort_t* wl   = (ushort_t*)(base + 37748736);      // path A: 36 MB, path B: 6.3 MB
    float*    bqkv; ushort_t* lmwb; float* mbias;
    if (onep) {
        bqkv  = (float*)(base + 75497472);               // 36,864 B (6 x 1536)
        lmwb  = (ushort_t*)(base + 75534336);            // 524,288
        mbias = (float*)(base + 76058624);               // 16,384 -> end 76,075,008
    } else {
        bqkv  = (float*)(base + 44040192);
        lmwb  = (ushort_t*)(base + 44046336);
        mbias = (float*)(base + 44570624);
    }

    cvt_simple<<<256, 256, 0, stream>>>(lmw, lmwb);
    maskbias_kernel<<<16, 256, 0, stream>>>(am, mbias);
    embed_kernel<<<NROWS, 512, 0, stream>>>(ids, emb, h, hb);
    if (onep)
        cvt_all<<<18432, 256, 0, stream>>>(wq, wk, wv, wo, w1, w2, bq, bk, bv, wl, bqkv);

    for (int l = 0; l < NLAYER; ++l) {
        const size_t dd = (size_t)l * 262144;
        const size_t fd = (size_t)l * 1048576;
        ushort_t* lw; const float* lb;
        if (onep) {
            lw = wl + (size_t)l * 3145728;
            lb = bqkv + l * 1536;
        } else {
            cvt_layer<<<3072, 256, 0, stream>>>(wq + dd, wk + dd, wv + dd, wo + dd,
                                                w1 + fd, w2 + fd,
                                                bq + l * 512, bk + l * 512, bv + l * 512,
                                                wl, bqkv);
            lw = wl;
            lb = bqkv;
        }
        // QKV fused GEMM, 128x128 tile (V written transposed to vtg by epilogue)
        gemm_kernel<128, 128, false, false, true, true><<<dim3(12, 32), 256, 0, stream>>>(
            hb, lw, lb, nullptr, qkvb, vtg, NROWS, 1536, 512);

        attn_kernel<<<512, 256, 0, stream>>>(qkvb, vtg, mbias, ob);

        gemm_kernel<64, 64, false, true, false, false><<<dim3(8, 64), 256, 0, stream>>>(
            ob, lw + 786432, bo + l * 512, h, h2, nullptr, NROWS, 512, 512);
        ln_kernel<<<NROWS, 512, 0, stream>>>(h2, ln1g + l * 512, ln1b + l * 512, h, hb);

        gemm_kernel<128, 128, true, false, true, false><<<dim3(16, 32), 256, 0, stream>>>(
            hb, lw + 1048576, b1 + l * 2048, nullptr, fbuf, nullptr, NROWS, 2048, 512);
        gemm_kernel<64, 64, false, true, false, false><<<dim3(8, 64), 256, 0, stream>>>(
            fbuf, lw + 2097152, b2 + l * 512, h, h2, nullptr, NROWS, 512, 2048);
        ln_kernel<<<NROWS, 512, 0, stream>>>(h2, ln2g + l * 512, ln2b + l * 512, h, hb);
    }

    ln_kernel<<<NROWS, 512, 0, stream>>>(h, lnfg, lnfb, h, hb);
    gemm_kernel<64, 64, false, false, false, false><<<dim3(8, 64), 256, 0, stream>>>(
        hb, lmwb, nullptr, nullptr, d_out, nullptr, NROWS, 512, 512);
}

// Round 13
// 745.228 us; speedup vs baseline: 1.0347x; 1.0347x over previous
//
#include <hip/hip_runtime.h>
#include <math.h>

#define D_MODEL 512
#define NHEAD   8
#define DKH     64
#define NLAYER  6
#define FFDIM   2048
#define VOCAB   512
#define BB      4
#define SS      1024
#define NROWS   4096

typedef unsigned short ushort_t;
typedef short short8 __attribute__((ext_vector_type(8)));
typedef float f32x4  __attribute__((ext_vector_type(4)));

__device__ __forceinline__ float bf2f(ushort_t u) {
    union { float f; unsigned int i; } x; x.i = ((unsigned int)u) << 16; return x.f;
}
__device__ __forceinline__ ushort_t f2bf(float f) {
    union { float f; unsigned int i; } x; x.f = f;
    unsigned int r = x.i + 0x7FFFu + ((x.i >> 16) & 1u);
    return (ushort_t)(r >> 16);
}
__device__ __forceinline__ void gload_lds16(const void* g, void* l) {
    __builtin_amdgcn_global_load_lds(
        (const __attribute__((address_space(1))) void*)g,
        (__attribute__((address_space(3))) void*)l, 16, 0, 0);
}
// counted vmcnt wait (T4): wait until at most N vector-memory ops outstanding
template<int N> __device__ __forceinline__ void waitcnt_vm() {
    if constexpr (N == 0)      asm volatile("s_waitcnt vmcnt(0)" ::: "memory");
    else if constexpr (N == 4) asm volatile("s_waitcnt vmcnt(4)" ::: "memory");
    else if constexpr (N == 6) asm volatile("s_waitcnt vmcnt(6)" ::: "memory");
    else if constexpr (N == 8) asm volatile("s_waitcnt vmcnt(8)" ::: "memory");
}
__device__ __forceinline__ void block_barrier() {
    __builtin_amdgcn_s_barrier();
    __builtin_amdgcn_sched_barrier(0);   // pin: no memory op crosses the barrier
}

// ------------------------------------------------------------- weight convert
// Per-layer (R9 config): qkv 786432 | wo 262144 | w1 1048576 | w2 1048576
__global__ __launch_bounds__(256) void cvt_layer(
    const float* __restrict__ wq, const float* __restrict__ wk, const float* __restrict__ wv,
    const float* __restrict__ wo, const float* __restrict__ w1, const float* __restrict__ w2,
    const float* __restrict__ bq, const float* __restrict__ bk, const float* __restrict__ bv,
    ushort_t* __restrict__ wl, float* __restrict__ bqkv)
{
    int idx = blockIdx.x * 256 + threadIdx.x;
    int e = idx * 4;
    float4 v;
    if (e < 786432) {
        if (e < 262144)       v = *(const float4*)(wq + e);
        else if (e < 524288)  v = *(const float4*)(wk + (e - 262144));
        else                  v = *(const float4*)(wv + (e - 524288));
    } else if (e < 1048576)   v = *(const float4*)(wo + (e - 786432));
    else if (e < 2097152)     v = *(const float4*)(w1 + (e - 1048576));
    else                      v = *(const float4*)(w2 + (e - 2097152));
    union { ushort_t u[4]; uint2 q; } pk;
    pk.u[0] = f2bf(v.x); pk.u[1] = f2bf(v.y); pk.u[2] = f2bf(v.z); pk.u[3] = f2bf(v.w);
    *(uint2*)(wl + e) = pk.q;
    if (idx < 384) {
        int b4 = idx * 4;
        float4 bv4;
        if (b4 < 512)       bv4 = *(const float4*)(bq + b4);
        else if (b4 < 1024) bv4 = *(const float4*)(bk + (b4 - 512));
        else                bv4 = *(const float4*)(bv + (b4 - 1024));
        *(float4*)(bqkv + b4) = bv4;
    }
}

__global__ __launch_bounds__(256) void cvt_simple(
    const float* __restrict__ src, ushort_t* __restrict__ dst)
{
    int e = (blockIdx.x * 256 + threadIdx.x) * 4;
    float4 v = *(const float4*)(src + e);
    union { ushort_t u[4]; uint2 q; } pk;
    pk.u[0] = f2bf(v.x); pk.u[1] = f2bf(v.y); pk.u[2] = f2bf(v.z); pk.u[3] = f2bf(v.w);
    *(uint2*)(dst + e) = pk.q;
}

__global__ __launch_bounds__(256) void maskbias_kernel(
    const int* __restrict__ am, float* __restrict__ mb)
{
    int i = blockIdx.x * 256 + threadIdx.x;
    if (i < NROWS) mb[i] = am[i] ? 0.f : -1e9f;
}

// ---------------------------------------------------------------- embedding
__global__ __launch_bounds__(512) void embed_kernel(
    const int* __restrict__ ids, const float* __restrict__ emb,
    float* __restrict__ xf, ushort_t* __restrict__ xb)
{
    int row = blockIdx.x;
    int d   = threadIdx.x;
    int s   = row & (SS - 1);
    int tok = ids[row];
    float div = expf(-(float)(d & ~1) * 0.0179889460390586f);
    float arg = (float)s * div;
    float pe  = (d & 1) ? cosf(arg) : sinf(arg);
    float v = emb[(size_t)tok * D_MODEL + d] * 22.62741699796952f + pe;
    xf[(size_t)row * D_MODEL + d] = v;
    xb[(size_t)row * D_MODEL + d] = f2bf(v);
}

// ---------------------------------------------------------------- layernorm
__global__ __launch_bounds__(512) void ln_kernel(
    const float* __restrict__ x, const float* __restrict__ g,
    const float* __restrict__ b, float* __restrict__ outf, ushort_t* __restrict__ outb)
{
    int row = blockIdx.x;
    int d   = threadIdx.x;
    int wave = d >> 6, lane = d & 63;
    __shared__ float red[8];

    float v = x[(size_t)row * D_MODEL + d];
    float s = v;
#pragma unroll
    for (int o = 32; o > 0; o >>= 1) s += __shfl_xor(s, o);
    if (lane == 0) red[wave] = s;
    __syncthreads();
    float tot = 0.f;
#pragma unroll
    for (int i = 0; i < 8; ++i) tot += red[i];
    float mu = tot * (1.0f / D_MODEL);
    float c  = v - mu;
    __syncthreads();
    float s2 = c * c;
#pragma unroll
    for (int o = 32; o > 0; o >>= 1) s2 += __shfl_xor(s2, o);
    if (lane == 0) red[wave] = s2;
    __syncthreads();
    float tot2 = 0.f;
#pragma unroll
    for (int i = 0; i < 8; ++i) tot2 += red[i];
    float var = tot2 * (1.0f / D_MODEL);
    float y = c * (1.0f / sqrtf(var + 1e-5f)) * g[d] + b[d];
    outf[(size_t)row * D_MODEL + d] = y;
    outb[(size_t)row * D_MODEL + d] = f2bf(y);
}

// ---------------------------------------------------------------- MFMA GEMM
// T4 counted-vmcnt double-buffer: STAGE(k+1) issued, then s_waitcnt vmcnt(N)
// (N = loads just issued, so only tile k's loads are awaited), raw s_barrier
// (NOT __syncthreads -- that force-drains vmcnt to 0), COMPUTE(k), barrier.
// Next tile's loads stay in flight across both barriers. BK=64, XOR
// source-swizzled LDS. No setprio (m190: hurts lockstep GEMM).
template<int BM, int BN, bool RELU, bool RES, bool OBF16, bool VT>
__global__ __launch_bounds__(256) void gemm_kernel(
    const ushort_t* __restrict__ A, const ushort_t* __restrict__ W,
    const float* __restrict__ bias, const float* __restrict__ res,
    void* __restrict__ out, ushort_t* __restrict__ vtg, int M, int N, int K)
{
    constexpr int WMT = BM / 2, WNT = BN / 2;
    constexpr int FM = WMT / 16, FN = WNT / 16;
    constexpr int ISSA = BM / 32, ISSB = BN / 32;
    constexpr int NWAIT = ISSA + ISSB;
    __shared__ ushort_t As[2][BM * 64];
    __shared__ ushort_t Bs[2][BN * 64];

    const int t = threadIdx.x;
    const int w = t >> 6, lane = t & 63;
    const int wr = w >> 1, wc = w & 1;
    const int col0 = blockIdx.x * BN;
    const int row0 = blockIdx.y * BM;
    const int lrow = lane & 15, kg = lane >> 4;
    const int srow = t >> 3;                       // 0..31
    const int sk8  = (t & 7) ^ ((t >> 3) & 7);     // pre-swizzled source k8

    f32x4 acc[FM][FN];
#pragma unroll
    for (int m = 0; m < FM; ++m)
#pragma unroll
        for (int n = 0; n < FN; ++n) acc[m][n] = (f32x4){0.f, 0.f, 0.f, 0.f};

    auto STAGE = [&](int buf, int k0) {
#pragma unroll
        for (int i = 0; i < ISSA; ++i)
            gload_lds16(A + (size_t)(row0 + i * 32 + srow) * K + k0 + sk8 * 8,
                        (char*)&As[buf][0] + i * 4096 + t * 16);
#pragma unroll
        for (int i = 0; i < ISSB; ++i)
            gload_lds16(W + (size_t)(col0 + i * 32 + srow) * K + k0 + sk8 * 8,
                        (char*)&Bs[buf][0] + i * 4096 + t * 16);
    };

    STAGE(0, 0);
    int buf = 0;
    for (int k0 = 0; k0 < K; k0 += 64) {
        if (k0 + 64 < K) { STAGE(buf ^ 1, k0 + 64); waitcnt_vm<NWAIT>(); }
        else             { waitcnt_vm<0>(); }
        block_barrier();                 // tile k0 resident for all waves
#pragma unroll
        for (int kk = 0; kk < 2; ++kk) {
            short8 af[FM], bfv[FN];
#pragma unroll
            for (int m = 0; m < FM; ++m) {
                const int row = wr * WMT + m * 16 + lrow;
                af[m] = *(const short8*)&As[buf][row * 64 + (((kk * 4 + kg) ^ (lrow & 7)) << 3)];
            }
#pragma unroll
            for (int n = 0; n < FN; ++n) {
                const int col = wc * WNT + n * 16 + lrow;
                bfv[n] = *(const short8*)&Bs[buf][col * 64 + (((kk * 4 + kg) ^ (lrow & 7)) << 3)];
            }
#pragma unroll
            for (int m = 0; m < FM; ++m)
#pragma unroll
                for (int n = 0; n < FN; ++n)
                    acc[m][n] = __builtin_amdgcn_mfma_f32_16x16x32_bf16(
                        af[m], bfv[n], acc[m][n], 0, 0, 0);
        }
        block_barrier();                 // all reads of buf done before overwrite
        buf ^= 1;
    }

    const int lrow4 = (lane >> 4) * 4;
    const int lcol  = lane & 15;
#pragma unroll
    for (int m = 0; m < FM; ++m)
#pragma unroll
        for (int n = 0; n < FN; ++n) {
            const int col = col0 + wc * WNT + n * 16 + lcol;
            const float bv = bias ? bias[col] : 0.f;
            const int row_base = row0 + wr * WMT + m * 16 + lrow4;
            if (VT && col >= 1024) {
                const int vh = (col - 1024) >> 6;
                const int vd = (col - 1024) & 63;
                const int bq = row_base >> 10;
                const int s0 = row_base & 1023;
                union { ushort_t u[4]; uint2 q; } pk;
#pragma unroll
                for (int j = 0; j < 4; ++j) pk.u[j] = f2bf(acc[m][n][j] + bv);
                *(uint2*)(vtg + ((size_t)(bq * 8 + vh) * 64 + vd) * 1024 + s0) = pk.q;
            } else {
#pragma unroll
                for (int j = 0; j < 4; ++j) {
                    const int row = row_base + j;
                    float v = acc[m][n][j] + bv;
                    if (RES)  v += res[(size_t)row * N + col];
                    if (RELU) v = fmaxf(v, 0.f);
                    if (OBF16) ((ushort_t*)out)[(size_t)row * N + col] = f2bf(v);
                    else       ((float*)out)[(size_t)row * N + col] = v;
                }
            }
        }
}

// ---------------------------------------------------------------- attention
// R9 structure + T4 counted-vmcnt pipeline: STAGE(kt+1); vmcnt(4); barrier;
// COMPUTE(kt); barrier -- next tile's 4 loads stay in flight across barriers.
// Swapped-operand MFMA flash attention, zero-transport P handoff, LDS-staged
// dbuf K/V. K swizzle f(row)=(row>>3)&7; V swizzle f(row)=row&7. No setprio.
__global__ __launch_bounds__(256) void attn_kernel(
    const ushort_t* __restrict__ qkv, const ushort_t* __restrict__ vtg,
    const float* __restrict__ mbias, ushort_t* __restrict__ o)
{
    __shared__ ushort_t Kl[2][64 * 64];   // [key][d]
    __shared__ ushort_t Vl[2][64 * 64];   // [d][key]

    const int t = threadIdx.x, w = t >> 6, l = t & 63;
    const int bid = blockIdx.x;
    const int qt = 15 - (bid >> 5);        // heavy tiles first
    const int bh = bid & 31, b = bh >> 3, h = bh & 7;
    const int q0 = qt * 64;
    const int lg = l >> 4, lr = l & 15;
    const int qi = q0 + w * 16 + lr;       // this lane's query

    const ushort_t* qrow = qkv + (size_t)(b * SS + qi) * 1536 + h * 64;
    const short8 qa0 = *(const short8*)(qrow + lg * 8);
    const short8 qa1 = *(const short8*)(qrow + 32 + lg * 8);

    float m_run = -1e30f, l_run = 0.f;
    f32x4 oacc[4];
#pragma unroll
    for (int nb = 0; nb < 4; ++nb) oacc[nb] = (f32x4){0.f, 0.f, 0.f, 0.f};

    const int krow = 32 * ((lr >> 1) & 1) + 8 * (lr >> 2) + (lr & 1);
    const ushort_t* qkvK = qkv + (size_t)(b * SS) * 1536 + 512 + h * 64;
    const ushort_t* vtgB = vtg + (size_t)bh * 64 * 1024;
    const float*    mb0  = mbias + b * SS + 8 * lg;

    const int sr0 = t >> 3, sc0 = t & 7;

    auto STAGE = [&](int buf, int kt) {
#pragma unroll
        for (int p = 0; p < 2; ++p) {
            const int row = p * 32 + sr0;
            const int ch  = sc0 ^ ((row >> 3) & 7);                 // K swizzle
            gload_lds16(qkvK + (size_t)(kt * 64 + row) * 1536 + ch * 8,
                        (char*)&Kl[buf][0] + (p * 256 + t) * 16);
        }
#pragma unroll
        for (int p = 0; p < 2; ++p) {
            const int row = p * 32 + sr0;
            const int ch  = sc0 ^ (row & 7);                        // V swizzle
            gload_lds16(vtgB + (size_t)row * 1024 + kt * 64 + ch * 8,
                        (char*)&Vl[buf][0] + (p * 256 + t) * 16);
        }
    };

    auto COMPUTE = [&](int buf, int kt) {
        const ushort_t* Kb = &Kl[buf][0];
        const ushort_t* Vb = &Vl[buf][0];
        short8 kf[8], vf[8];
#pragma unroll
        for (int nf = 0; nf < 4; ++nf) {
            const int row = 2 * nf + krow;
            const int sw  = (row >> 3) & 7;
            kf[2 * nf]     = *(const short8*)&Kb[row * 64 + ((lg ^ sw) << 3)];
            kf[2 * nf + 1] = *(const short8*)&Kb[row * 64 + (((4 + lg) ^ sw) << 3)];
        }
#pragma unroll
        for (int nb = 0; nb < 4; ++nb) {
            const int row = 16 * nb + lr;
            const int sw  = row & 7;
            vf[2 * nb]     = *(const short8*)&Vb[row * 64 + ((lg ^ sw) << 3)];
            vf[2 * nb + 1] = *(const short8*)&Vb[row * 64 + (((4 + lg) ^ sw) << 3)];
        }
        const float* mrow = mb0 + kt * 64;
        const float4 mA = *(const float4*)(mrow);
        const float4 mB = *(const float4*)(mrow + 4);
        const float4 mC = *(const float4*)(mrow + 32);
        const float4 mD = *(const float4*)(mrow + 36);
        // S = K * Q^T
        f32x4 s[4];
#pragma unroll
        for (int nf = 0; nf < 4; ++nf) {
            f32x4 a = (f32x4){0.f, 0.f, 0.f, 0.f};
            a = __builtin_amdgcn_mfma_f32_16x16x32_bf16(kf[2 * nf],     qa0, a, 0, 0, 0);
            a = __builtin_amdgcn_mfma_f32_16x16x32_bf16(kf[2 * nf + 1], qa1, a, 0, 0, 0);
            s[nf] = a;
        }
        const bool diag = (kt == qt);
        const int kbase = kt * 64 + 8 * lg;
#pragma unroll
        for (int nf = 0; nf < 4; ++nf) {
#pragma unroll
            for (int r = 0; r < 4; ++r) {
                const int e = r & 1, oo = (r >> 1) & 1;
                const int idx = 2 * nf + e;              // 0..7
                const float bias = oo ? (idx < 4 ? ((const float*)&mC)[idx] : ((const float*)&mD)[idx - 4])
                                      : (idx < 4 ? ((const float*)&mA)[idx] : ((const float*)&mB)[idx - 4]);
                float sv = s[nf][r] * 0.125f + bias;
                if (diag && (kbase + idx + 32 * oo) > qi) sv = -1e9f;
                s[nf][r] = sv;
            }
        }
        float pm[4];
#pragma unroll
        for (int nf = 0; nf < 4; ++nf)
            pm[nf] = fmaxf(fmaxf(s[nf][0], s[nf][1]), fmaxf(s[nf][2], s[nf][3]));
        float mx = fmaxf(fmaxf(pm[0], pm[1]), fmaxf(pm[2], pm[3]));
        mx = fmaxf(mx, __shfl_xor(mx, 16));
        mx = fmaxf(mx, __shfl_xor(mx, 32));
        const float mnew = fmaxf(m_run, mx);
        const float rs   = __expf(m_run - mnew);
        m_run = mnew;
        float ps[4];
#pragma unroll
        for (int nf = 0; nf < 4; ++nf) {
#pragma unroll
            for (int r = 0; r < 4; ++r) s[nf][r] = __expf(s[nf][r] - mnew);
            ps[nf] = (s[nf][0] + s[nf][1]) + (s[nf][2] + s[nf][3]);
        }
        float tsum = (ps[0] + ps[1]) + (ps[2] + ps[3]);
        tsum += __shfl_xor(tsum, 16);
        tsum += __shfl_xor(tsum, 32);
        l_run = l_run * rs + tsum;
#pragma unroll
        for (int nb = 0; nb < 4; ++nb)
#pragma unroll
            for (int r = 0; r < 4; ++r) oacc[nb][r] *= rs;
        union { unsigned u[4]; short8 s8; } pa0u, pa1u;
#pragma unroll
        for (int nf = 0; nf < 4; ++nf) {
            pa0u.u[nf] = ((unsigned)f2bf(s[nf][1]) << 16) | (unsigned)f2bf(s[nf][0]);
            pa1u.u[nf] = ((unsigned)f2bf(s[nf][3]) << 16) | (unsigned)f2bf(s[nf][2]);
        }
#pragma unroll
        for (int nb = 0; nb < 4; ++nb) {
            oacc[nb] = __builtin_amdgcn_mfma_f32_16x16x32_bf16(vf[2 * nb],     pa0u.s8, oacc[nb], 0, 0, 0);
            oacc[nb] = __builtin_amdgcn_mfma_f32_16x16x32_bf16(vf[2 * nb + 1], pa1u.s8, oacc[nb], 0, 0, 0);
        }
    };

    STAGE(0, 0);
    int buf = 0;
    for (int kt = 0; kt <= qt; ++kt) {
        if (kt < qt) { STAGE(buf ^ 1, kt + 1); waitcnt_vm<4>(); }
        else         { waitcnt_vm<0>(); }
        block_barrier();                 // tile kt resident for all waves
        COMPUTE(buf, kt);
        block_barrier();                 // all reads of buf done before overwrite
        buf ^= 1;
    }

    const float inv = 1.0f / l_run;
    ushort_t* orow = o + (size_t)(b * SS + qi) * 512 + h * 64;
#pragma unroll
    for (int nb = 0; nb < 4; ++nb) {
        union { ushort_t u[4]; uint2 q; } pk;
#pragma unroll
        for (int r = 0; r < 4; ++r) pk.u[r] = f2bf(oacc[nb][r] * inv);
        *(uint2*)(orow + nb * 16 + 4 * lg) = pk.q;
    }
}

// ---------------------------------------------------------------- launch
extern "C" void kernel_launch(void* const* d_in, const int* in_sizes, int n_in,
                              void* d_out, int out_size, void* d_ws, size_t ws_size,
                              hipStream_t stream)
{
    const int*   ids   = (const int*)d_in[0];
    const int*   am    = (const int*)d_in[1];
    const float* emb   = (const float*)d_in[2];
    const float* wq    = (const float*)d_in[3];
    const float* bq    = (const float*)d_in[4];
    const float* wk    = (const float*)d_in[5];
    const float* bk    = (const float*)d_in[6];
    const float* wv    = (const float*)d_in[7];
    const float* bv    = (const float*)d_in[8];
    const float* wo    = (const float*)d_in[9];
    const float* bo    = (const float*)d_in[10];
    const float* ln1g  = (const float*)d_in[11];
    const float* ln1b  = (const float*)d_in[12];
    const float* w1    = (const float*)d_in[13];
    const float* b1    = (const float*)d_in[14];
    const float* w2    = (const float*)d_in[15];
    const float* b2    = (const float*)d_in[16];
    const float* ln2g  = (const float*)d_in[17];
    const float* ln2b  = (const float*)d_in[18];
    const float* lnfg  = (const float*)d_in[19];
    const float* lnfb  = (const float*)d_in[20];
    const float* lmw   = (const float*)d_in[21];

    char* base = (char*)d_ws;
    float*    h    = (float*)(base);                    //  8 MB
    float*    h2   = (float*)(base + 8388608);          //  8 MB (attn: vtg 4MB)
    ushort_t* hb   = (ushort_t*)(base + 16777216);      //  4 MB
    ushort_t* act  = (ushort_t*)(base + 20971520);      // 16 MB shared
    ushort_t* qkvb = act;                               //   12 MB
    ushort_t* ob   = act + 6291456;                     //    4 MB
    ushort_t* fbuf = act;                               //   16 MB (after attn phase)
    ushort_t* wl   = (ushort_t*)(base + 37748736);      //  6,291,456
    float*    bqkv = (float*)(base + 44040192);         //      6,144
    ushort_t* lmwb = (ushort_t*)(base + 44046336);      //    524,288
    float*    mbias= (float*)(base + 44570624);         //     16,384
    ushort_t* vtg  = (ushort_t*)h2;                     //    4 MB, attn-phase only

    cvt_simple<<<256, 256, 0, stream>>>(lmw, lmwb);
    maskbias_kernel<<<16, 256, 0, stream>>>(am, mbias);
    embed_kernel<<<NROWS, 512, 0, stream>>>(ids, emb, h, hb);

    for (int l = 0; l < NLAYER; ++l) {
        const size_t dd = (size_t)l * 262144;
        const size_t fd = (size_t)l * 1048576;
        cvt_layer<<<3072, 256, 0, stream>>>(wq + dd, wk + dd, wv + dd, wo + dd,
                                            w1 + fd, w2 + fd,
                                            bq + l * 512, bk + l * 512, bv + l * 512,
                                            wl, bqkv);
        // QKV fused GEMM (V written transposed to vtg by epilogue)
        gemm_kernel<64, 128, false, false, true, true><<<dim3(12, 64), 256, 0, stream>>>(
            hb, wl, bqkv, nullptr, qkvb, vtg, NROWS, 1536, 512);

        attn_kernel<<<512, 256, 0, stream>>>(qkvb, vtg, mbias, ob);

        gemm_kernel<64, 64, false, true, false, false><<<dim3(8, 64), 256, 0, stream>>>(
            ob, wl + 786432, bo + l * 512, h, h2, nullptr, NROWS, 512, 512);
        ln_kernel<<<NROWS, 512, 0, stream>>>(h2, ln1g + l * 512, ln1b + l * 512, h, hb);

        gemm_kernel<64, 128, true, false, true, false><<<dim3(16, 64), 256, 0, stream>>>(
            hb, wl + 1048576, b1 + l * 2048, nullptr, fbuf, nullptr, NROWS, 2048, 512);
        gemm_kernel<64, 64, false, true, false, false><<<dim3(8, 64), 256, 0, stream>>>(
            fbuf, wl + 2097152, b2 + l * 512, h, h2, nullptr, NROWS, 512, 2048);
        ln_kernel<<<NROWS, 512, 0, stream>>>(h2, ln2g + l * 512, ln2b + l * 512, h, hb);
    }

    ln_kernel<<<NROWS, 512, 0, stream>>>(h, lnfg, lnfb, h, hb);
    gemm_kernel<64, 64, false, false, false, false><<<dim3(8, 64), 256, 0, stream>>>(
        hb, lmwb, nullptr, nullptr, d_out, nullptr, NROWS, 512, 512);
}

// Round 14
// 711.447 us; speedup vs baseline: 1.0838x; 1.0475x over previous
//
#include <hip/hip_runtime.h>
#include <math.h>

#define D_MODEL 512
#define NHEAD   8
#define DKH     64
#define NLAYER  6
#define FFDIM   2048
#define VOCAB   512
#define BB      4
#define SS      1024
#define NROWS   4096

typedef unsigned short ushort_t;
typedef short short8 __attribute__((ext_vector_type(8)));
typedef float f32x4  __attribute__((ext_vector_type(4)));

__device__ __forceinline__ float bf2f(ushort_t u) {
    union { float f; unsigned int i; } x; x.i = ((unsigned int)u) << 16; return x.f;
}
__device__ __forceinline__ ushort_t f2bf(float f) {
    union { float f; unsigned int i; } x; x.f = f;
    unsigned int r = x.i + 0x7FFFu + ((x.i >> 16) & 1u);
    return (ushort_t)(r >> 16);
}
__device__ __forceinline__ void gload_lds16(const void* g, void* l) {
    __builtin_amdgcn_global_load_lds(
        (const __attribute__((address_space(1))) void*)g,
        (__attribute__((address_space(3))) void*)l, 16, 0, 0);
}
__device__ __forceinline__ void block_barrier() {
    __builtin_amdgcn_s_barrier();
    __builtin_amdgcn_sched_barrier(0);
}

// ------------------------------------------------------------- weight convert
// One-shot: all 6 layers in one dispatch.
// Per-layer layout: qkv 786432 | wo 262144 | w1 1048576 | w2 1048576
__global__ __launch_bounds__(256) void cvt_all(
    const float* __restrict__ wq, const float* __restrict__ wk, const float* __restrict__ wv,
    const float* __restrict__ wo, const float* __restrict__ w1, const float* __restrict__ w2,
    const float* __restrict__ bq, const float* __restrict__ bk, const float* __restrict__ bv,
    ushort_t* __restrict__ wl, float* __restrict__ bqkv)
{
    int idx = blockIdx.x * 256 + threadIdx.x;   // quad id, 4,718,592 total
    int e = idx * 4;
    int l = e / 3145728;
    int off = e - l * 3145728;
    float4 v;
    if (off < 786432) {
        if (off < 262144)       v = *(const float4*)(wq + l * 262144 + off);
        else if (off < 524288)  v = *(const float4*)(wk + l * 262144 + (off - 262144));
        else                    v = *(const float4*)(wv + l * 262144 + (off - 524288));
    } else if (off < 1048576)   v = *(const float4*)(wo + l * 262144 + (off - 786432));
    else if (off < 2097152)     v = *(const float4*)(w1 + l * 1048576 + (off - 1048576));
    else                        v = *(const float4*)(w2 + l * 1048576 + (off - 2097152));
    union { ushort_t u[4]; uint2 q; } pk;
    pk.u[0] = f2bf(v.x); pk.u[1] = f2bf(v.y); pk.u[2] = f2bf(v.z); pk.u[3] = f2bf(v.w);
    *(uint2*)(wl + e) = pk.q;
    if (idx < 2304) {           // 6 layers x 1536 qkv-bias floats
        int b4 = idx * 4;
        int bl = b4 / 1536;
        int r  = b4 - bl * 1536;
        float4 bv4;
        if (r < 512)       bv4 = *(const float4*)(bq + bl * 512 + r);
        else if (r < 1024) bv4 = *(const float4*)(bk + bl * 512 + (r - 512));
        else               bv4 = *(const float4*)(bv + bl * 512 + (r - 1024));
        *(float4*)(bqkv + b4) = bv4;
    }
}

// Per-layer fallback (if ws too small for one-shot)
__global__ __launch_bounds__(256) void cvt_layer(
    const float* __restrict__ wq, const float* __restrict__ wk, const float* __restrict__ wv,
    const float* __restrict__ wo, const float* __restrict__ w1, const float* __restrict__ w2,
    const float* __restrict__ bq, const float* __restrict__ bk, const float* __restrict__ bv,
    ushort_t* __restrict__ wl, float* __restrict__ bqkv)
{
    int idx = blockIdx.x * 256 + threadIdx.x;
    int e = idx * 4;
    float4 v;
    if (e < 786432) {
        if (e < 262144)       v = *(const float4*)(wq + e);
        else if (e < 524288)  v = *(const float4*)(wk + (e - 262144));
        else                  v = *(const float4*)(wv + (e - 524288));
    } else if (e < 1048576)   v = *(const float4*)(wo + (e - 786432));
    else if (e < 2097152)     v = *(const float4*)(w1 + (e - 1048576));
    else                      v = *(const float4*)(w2 + (e - 2097152));
    union { ushort_t u[4]; uint2 q; } pk;
    pk.u[0] = f2bf(v.x); pk.u[1] = f2bf(v.y); pk.u[2] = f2bf(v.z); pk.u[3] = f2bf(v.w);
    *(uint2*)(wl + e) = pk.q;
    if (idx < 384) {
        int b4 = idx * 4;
        float4 bv4;
        if (b4 < 512)       bv4 = *(const float4*)(bq + b4);
        else if (b4 < 1024) bv4 = *(const float4*)(bk + (b4 - 512));
        else                bv4 = *(const float4*)(bv + (b4 - 1024));
        *(float4*)(bqkv + b4) = bv4;
    }
}

__global__ __launch_bounds__(256) void cvt_simple(
    const float* __restrict__ src, ushort_t* __restrict__ dst)
{
    int e = (blockIdx.x * 256 + threadIdx.x) * 4;
    float4 v = *(const float4*)(src + e);
    union { ushort_t u[4]; uint2 q; } pk;
    pk.u[0] = f2bf(v.x); pk.u[1] = f2bf(v.y); pk.u[2] = f2bf(v.z); pk.u[3] = f2bf(v.w);
    *(uint2*)(dst + e) = pk.q;
}

__global__ __launch_bounds__(256) void maskbias_kernel(
    const int* __restrict__ am, float* __restrict__ mb)
{
    int i = blockIdx.x * 256 + threadIdx.x;
    if (i < NROWS) mb[i] = am[i] ? 0.f : -1e9f;
}

// ---------------------------------------------------------------- embedding
__global__ __launch_bounds__(512) void embed_kernel(
    const int* __restrict__ ids, const float* __restrict__ emb,
    float* __restrict__ xf, ushort_t* __restrict__ xb)
{
    int row = blockIdx.x;
    int d   = threadIdx.x;
    int s   = row & (SS - 1);
    int tok = ids[row];
    float div = expf(-(float)(d & ~1) * 0.0179889460390586f);
    float arg = (float)s * div;
    float pe  = (d & 1) ? cosf(arg) : sinf(arg);
    float v = emb[(size_t)tok * D_MODEL + d] * 22.62741699796952f + pe;
    xf[(size_t)row * D_MODEL + d] = v;
    xb[(size_t)row * D_MODEL + d] = f2bf(v);
}

// ---------------------------------------------------------------- layernorm
__global__ __launch_bounds__(512) void ln_kernel(
    const float* __restrict__ x, const float* __restrict__ g,
    const float* __restrict__ b, float* __restrict__ outf, ushort_t* __restrict__ outb)
{
    int row = blockIdx.x;
    int d   = threadIdx.x;
    int wave = d >> 6, lane = d & 63;
    __shared__ float red[8];

    float v = x[(size_t)row * D_MODEL + d];
    float s = v;
#pragma unroll
    for (int o = 32; o > 0; o >>= 1) s += __shfl_xor(s, o);
    if (lane == 0) red[wave] = s;
    __syncthreads();
    float tot = 0.f;
#pragma unroll
    for (int i = 0; i < 8; ++i) tot += red[i];
    float mu = tot * (1.0f / D_MODEL);
    float c  = v - mu;
    __syncthreads();
    float s2 = c * c;
#pragma unroll
    for (int o = 32; o > 0; o >>= 1) s2 += __shfl_xor(s2, o);
    if (lane == 0) red[wave] = s2;
    __syncthreads();
    float tot2 = 0.f;
#pragma unroll
    for (int i = 0; i < 8; ++i) tot2 += red[i];
    float var = tot2 * (1.0f / D_MODEL);
    float y = c * (1.0f / sqrtf(var + 1e-5f)) * g[d] + b[d];
    outf[(size_t)row * D_MODEL + d] = y;
    outb[(size_t)row * D_MODEL + d] = f2bf(y);
}

// ---------------------------------------------------------------- MFMA GEMM
// EXACT R9 structure (verified 723us config): single-buffer LDS, BK=64,
// XOR source-swizzled staging, __syncthreads loop, no setprio, no swizzle.
// Occupancy (24KB / 16KB LDS) beats explicit pipelining at these small-K
// L3-resident shapes (R10/R13 both regressed with dbuf).
template<int BM, int BN, bool RELU, bool RES, bool OBF16, bool VT>
__global__ __launch_bounds__(256) void gemm_kernel(
    const ushort_t* __restrict__ A, const ushort_t* __restrict__ W,
    const float* __restrict__ bias, const float* __restrict__ res,
    void* __restrict__ out, ushort_t* __restrict__ vtg, int M, int N, int K)
{
    constexpr int WMT = BM / 2, WNT = BN / 2;
    constexpr int FM = WMT / 16, FN = WNT / 16;
    constexpr int ISSA = BM / 32, ISSB = BN / 32;
    __shared__ ushort_t As[BM * 64];
    __shared__ ushort_t Bs[BN * 64];

    const int t = threadIdx.x;
    const int w = t >> 6, lane = t & 63;
    const int wr = w >> 1, wc = w & 1;
    const int col0 = blockIdx.x * BN;
    const int row0 = blockIdx.y * BM;
    const int lrow = lane & 15, kg = lane >> 4;
    const int srow = t >> 3;                       // 0..31
    const int sk8  = (t & 7) ^ ((t >> 3) & 7);     // pre-swizzled source k8

    f32x4 acc[FM][FN];
#pragma unroll
    for (int m = 0; m < FM; ++m)
#pragma unroll
        for (int n = 0; n < FN; ++n) acc[m][n] = (f32x4){0.f, 0.f, 0.f, 0.f};

    for (int k0 = 0; k0 < K; k0 += 64) {
#pragma unroll
        for (int i = 0; i < ISSA; ++i)
            gload_lds16(A + (size_t)(row0 + i * 32 + srow) * K + k0 + sk8 * 8,
                        (char*)As + i * 4096 + t * 16);
#pragma unroll
        for (int i = 0; i < ISSB; ++i)
            gload_lds16(W + (size_t)(col0 + i * 32 + srow) * K + k0 + sk8 * 8,
                        (char*)Bs + i * 4096 + t * 16);
        __syncthreads();
#pragma unroll
        for (int kk = 0; kk < 2; ++kk) {
            short8 af[FM], bfv[FN];
#pragma unroll
            for (int m = 0; m < FM; ++m) {
                const int row = wr * WMT + m * 16 + lrow;
                af[m] = *(const short8*)&As[row * 64 + (((kk * 4 + kg) ^ (lrow & 7)) << 3)];
            }
#pragma unroll
            for (int n = 0; n < FN; ++n) {
                const int col = wc * WNT + n * 16 + lrow;
                bfv[n] = *(const short8*)&Bs[col * 64 + (((kk * 4 + kg) ^ (lrow & 7)) << 3)];
            }
#pragma unroll
            for (int m = 0; m < FM; ++m)
#pragma unroll
                for (int n = 0; n < FN; ++n)
                    acc[m][n] = __builtin_amdgcn_mfma_f32_16x16x32_bf16(
                        af[m], bfv[n], acc[m][n], 0, 0, 0);
        }
        __syncthreads();
    }

    const int lrow4 = (lane >> 4) * 4;
    const int lcol  = lane & 15;
#pragma unroll
    for (int m = 0; m < FM; ++m)
#pragma unroll
        for (int n = 0; n < FN; ++n) {
            const int col = col0 + wc * WNT + n * 16 + lcol;
            const float bv = bias ? bias[col] : 0.f;
            const int row_base = row0 + wr * WMT + m * 16 + lrow4;
            if (VT && col >= 1024) {
                const int vh = (col - 1024) >> 6;
                const int vd = (col - 1024) & 63;
                const int bq = row_base >> 10;
                const int s0 = row_base & 1023;
                union { ushort_t u[4]; uint2 q; } pk;
#pragma unroll
                for (int j = 0; j < 4; ++j) pk.u[j] = f2bf(acc[m][n][j] + bv);
                *(uint2*)(vtg + ((size_t)(bq * 8 + vh) * 64 + vd) * 1024 + s0) = pk.q;
            } else {
#pragma unroll
                for (int j = 0; j < 4; ++j) {
                    const int row = row_base + j;
                    float v = acc[m][n][j] + bv;
                    if (RES)  v += res[(size_t)row * N + col];
                    if (RELU) v = fmaxf(v, 0.f);
                    if (OBF16) ((ushort_t*)out)[(size_t)row * N + col] = f2bf(v);
                    else       ((float*)out)[(size_t)row * N + col] = v;
                }
            }
        }
}

// ---------------------------------------------------------------- attention
// R9 structure + T4 counted-vmcnt (occupancy-neutral): STAGE(kt+1); vmcnt(4);
// s_barrier; COMPUTE(kt); s_barrier -- next tile's 4 loads stay in flight.
// Swapped-operand MFMA flash attention, zero-transport P handoff, LDS-staged
// dbuf K/V. K swizzle f(row)=(row>>3)&7; V swizzle f(row)=row&7. No setprio.
__global__ __launch_bounds__(256) void attn_kernel(
    const ushort_t* __restrict__ qkv, const ushort_t* __restrict__ vtg,
    const float* __restrict__ mbias, ushort_t* __restrict__ o)
{
    __shared__ ushort_t Kl[2][64 * 64];   // [key][d]
    __shared__ ushort_t Vl[2][64 * 64];   // [d][key]

    const int t = threadIdx.x, w = t >> 6, l = t & 63;
    const int bid = blockIdx.x;
    const int qt = 15 - (bid >> 5);        // heavy tiles first
    const int bh = bid & 31, b = bh >> 3, h = bh & 7;
    const int q0 = qt * 64;
    const int lg = l >> 4, lr = l & 15;
    const int qi = q0 + w * 16 + lr;       // this lane's query

    const ushort_t* qrow = qkv + (size_t)(b * SS + qi) * 1536 + h * 64;
    const short8 qa0 = *(const short8*)(qrow + lg * 8);
    const short8 qa1 = *(const short8*)(qrow + 32 + lg * 8);

    float m_run = -1e30f, l_run = 0.f;
    f32x4 oacc[4];
#pragma unroll
    for (int nb = 0; nb < 4; ++nb) oacc[nb] = (f32x4){0.f, 0.f, 0.f, 0.f};

    const int krow = 32 * ((lr >> 1) & 1) + 8 * (lr >> 2) + (lr & 1);
    const ushort_t* qkvK = qkv + (size_t)(b * SS) * 1536 + 512 + h * 64;
    const ushort_t* vtgB = vtg + (size_t)bh * 64 * 1024;
    const float*    mb0  = mbias + b * SS + 8 * lg;

    const int sr0 = t >> 3, sc0 = t & 7;

    auto STAGE = [&](int buf, int kt) {
#pragma unroll
        for (int p = 0; p < 2; ++p) {
            const int row = p * 32 + sr0;
            const int ch  = sc0 ^ ((row >> 3) & 7);                 // K swizzle
            gload_lds16(qkvK + (size_t)(kt * 64 + row) * 1536 + ch * 8,
                        (char*)&Kl[buf][0] + (p * 256 + t) * 16);
        }
#pragma unroll
        for (int p = 0; p < 2; ++p) {
            const int row = p * 32 + sr0;
            const int ch  = sc0 ^ (row & 7);                        // V swizzle
            gload_lds16(vtgB + (size_t)row * 1024 + kt * 64 + ch * 8,
                        (char*)&Vl[buf][0] + (p * 256 + t) * 16);
        }
    };

    auto COMPUTE = [&](int buf, int kt) {
        const ushort_t* Kb = &Kl[buf][0];
        const ushort_t* Vb = &Vl[buf][0];
        short8 kf[8], vf[8];
#pragma unroll
        for (int nf = 0; nf < 4; ++nf) {
            const int row = 2 * nf + krow;
            const int sw  = (row >> 3) & 7;
            kf[2 * nf]     = *(const short8*)&Kb[row * 64 + ((lg ^ sw) << 3)];
            kf[2 * nf + 1] = *(const short8*)&Kb[row * 64 + (((4 + lg) ^ sw) << 3)];
        }
#pragma unroll
        for (int nb = 0; nb < 4; ++nb) {
            const int row = 16 * nb + lr;
            const int sw  = row & 7;
            vf[2 * nb]     = *(const short8*)&Vb[row * 64 + ((lg ^ sw) << 3)];
            vf[2 * nb + 1] = *(const short8*)&Vb[row * 64 + (((4 + lg) ^ sw) << 3)];
        }
        const float* mrow = mb0 + kt * 64;
        const float4 mA = *(const float4*)(mrow);
        const float4 mB = *(const float4*)(mrow + 4);
        const float4 mC = *(const float4*)(mrow + 32);
        const float4 mD = *(const float4*)(mrow + 36);
        // S = K * Q^T
        f32x4 s[4];
#pragma unroll
        for (int nf = 0; nf < 4; ++nf) {
            f32x4 a = (f32x4){0.f, 0.f, 0.f, 0.f};
            a = __builtin_amdgcn_mfma_f32_16x16x32_bf16(kf[2 * nf],     qa0, a, 0, 0, 0);
            a = __builtin_amdgcn_mfma_f32_16x16x32_bf16(kf[2 * nf + 1], qa1, a, 0, 0, 0);
            s[nf] = a;
        }
        const bool diag = (kt == qt);
        const int kbase = kt * 64 + 8 * lg;
#pragma unroll
        for (int nf = 0; nf < 4; ++nf) {
#pragma unroll
            for (int r = 0; r < 4; ++r) {
                const int e = r & 1, oo = (r >> 1) & 1;
                const int idx = 2 * nf + e;              // 0..7
                const float bias = oo ? (idx < 4 ? ((const float*)&mC)[idx] : ((const float*)&mD)[idx - 4])
                                      : (idx < 4 ? ((const float*)&mA)[idx] : ((const float*)&mB)[idx - 4]);
                float sv = s[nf][r] * 0.125f + bias;
                if (diag && (kbase + idx + 32 * oo) > qi) sv = -1e9f;
                s[nf][r] = sv;
            }
        }
        float pm[4];
#pragma unroll
        for (int nf = 0; nf < 4; ++nf)
            pm[nf] = fmaxf(fmaxf(s[nf][0], s[nf][1]), fmaxf(s[nf][2], s[nf][3]));
        float mx = fmaxf(fmaxf(pm[0], pm[1]), fmaxf(pm[2], pm[3]));
        mx = fmaxf(mx, __shfl_xor(mx, 16));
        mx = fmaxf(mx, __shfl_xor(mx, 32));
        const float mnew = fmaxf(m_run, mx);
        const float rs   = __expf(m_run - mnew);
        m_run = mnew;
        float ps[4];
#pragma unroll
        for (int nf = 0; nf < 4; ++nf) {
#pragma unroll
            for (int r = 0; r < 4; ++r) s[nf][r] = __expf(s[nf][r] - mnew);
            ps[nf] = (s[nf][0] + s[nf][1]) + (s[nf][2] + s[nf][3]);
        }
        float tsum = (ps[0] + ps[1]) + (ps[2] + ps[3]);
        tsum += __shfl_xor(tsum, 16);
        tsum += __shfl_xor(tsum, 32);
        l_run = l_run * rs + tsum;
#pragma unroll
        for (int nb = 0; nb < 4; ++nb)
#pragma unroll
            for (int r = 0; r < 4; ++r) oacc[nb][r] *= rs;
        union { unsigned u[4]; short8 s8; } pa0u, pa1u;
#pragma unroll
        for (int nf = 0; nf < 4; ++nf) {
            pa0u.u[nf] = ((unsigned)f2bf(s[nf][1]) << 16) | (unsigned)f2bf(s[nf][0]);
            pa1u.u[nf] = ((unsigned)f2bf(s[nf][3]) << 16) | (unsigned)f2bf(s[nf][2]);
        }
#pragma unroll
        for (int nb = 0; nb < 4; ++nb) {
            oacc[nb] = __builtin_amdgcn_mfma_f32_16x16x32_bf16(vf[2 * nb],     pa0u.s8, oacc[nb], 0, 0, 0);
            oacc[nb] = __builtin_amdgcn_mfma_f32_16x16x32_bf16(vf[2 * nb + 1], pa1u.s8, oacc[nb], 0, 0, 0);
        }
    };

    STAGE(0, 0);
    int buf = 0;
    for (int kt = 0; kt <= qt; ++kt) {
        if (kt < qt) {
            STAGE(buf ^ 1, kt + 1);
            asm volatile("s_waitcnt vmcnt(4)" ::: "memory");   // await tile kt only
        } else {
            asm volatile("s_waitcnt vmcnt(0)" ::: "memory");
        }
        block_barrier();                 // tile kt resident for all waves
        COMPUTE(buf, kt);
        block_barrier();                 // all reads of buf done before overwrite
        buf ^= 1;
    }

    const float inv = 1.0f / l_run;
    ushort_t* orow = o + (size_t)(b * SS + qi) * 512 + h * 64;
#pragma unroll
    for (int nb = 0; nb < 4; ++nb) {
        union { ushort_t u[4]; uint2 q; } pk;
#pragma unroll
        for (int r = 0; r < 4; ++r) pk.u[r] = f2bf(oacc[nb][r] * inv);
        *(uint2*)(orow + nb * 16 + 4 * lg) = pk.q;
    }
}

// ---------------------------------------------------------------- launch
extern "C" void kernel_launch(void* const* d_in, const int* in_sizes, int n_in,
                              void* d_out, int out_size, void* d_ws, size_t ws_size,
                              hipStream_t stream)
{
    const int*   ids   = (const int*)d_in[0];
    const int*   am    = (const int*)d_in[1];
    const float* emb   = (const float*)d_in[2];
    const float* wq    = (const float*)d_in[3];
    const float* bq    = (const float*)d_in[4];
    const float* wk    = (const float*)d_in[5];
    const float* bk    = (const float*)d_in[6];
    const float* wv    = (const float*)d_in[7];
    const float* bv    = (const float*)d_in[8];
    const float* wo    = (const float*)d_in[9];
    const float* bo    = (const float*)d_in[10];
    const float* ln1g  = (const float*)d_in[11];
    const float* ln1b  = (const float*)d_in[12];
    const float* w1    = (const float*)d_in[13];
    const float* b1    = (const float*)d_in[14];
    const float* w2    = (const float*)d_in[15];
    const float* b2    = (const float*)d_in[16];
    const float* ln2g  = (const float*)d_in[17];
    const float* ln2b  = (const float*)d_in[18];
    const float* lnfg  = (const float*)d_in[19];
    const float* lnfb  = (const float*)d_in[20];
    const float* lmw   = (const float*)d_in[21];

    char* base = (char*)d_ws;
    float*    h    = (float*)(base);                    //  8 MB
    float*    h2   = (float*)(base + 8388608);          //  8 MB (attn: vtg 4MB)
    ushort_t* hb   = (ushort_t*)(base + 16777216);      //  4 MB
    ushort_t* act  = (ushort_t*)(base + 20971520);      // 16 MB shared
    ushort_t* qkvb = act;                               //   12 MB
    ushort_t* ob   = act + 6291456;                     //    4 MB
    ushort_t* fbuf = act;                               //   16 MB (after attn phase)
    ushort_t* vtg  = (ushort_t*)h2;                     //    4 MB, attn-phase only

    // weight-conversion scratch: one-shot if ws allows, else per-layer rotate
    const bool onep = ws_size >= (size_t)76100000;
    ushort_t* wl   = (ushort_t*)(base + 37748736);      // path A: 36 MB, path B: 6.3 MB
    float*    bqkv; ushort_t* lmwb; float* mbias;
    if (onep) {
        bqkv  = (float*)(base + 75497472);               // 36,864 B (6 x 1536)
        lmwb  = (ushort_t*)(base + 75534336);            // 524,288
        mbias = (float*)(base + 76058624);               // 16,384 -> end 76,075,008
    } else {
        bqkv  = (float*)(base + 44040192);
        lmwb  = (ushort_t*)(base + 44046336);
        mbias = (float*)(base + 44570624);
    }

    cvt_simple<<<256, 256, 0, stream>>>(lmw, lmwb);
    maskbias_kernel<<<16, 256, 0, stream>>>(am, mbias);
    embed_kernel<<<NROWS, 512, 0, stream>>>(ids, emb, h, hb);
    if (onep)
        cvt_all<<<18432, 256, 0, stream>>>(wq, wk, wv, wo, w1, w2, bq, bk, bv, wl, bqkv);

    for (int l = 0; l < NLAYER; ++l) {
        const size_t dd = (size_t)l * 262144;
        const size_t fd = (size_t)l * 1048576;
        ushort_t* lw; const float* lb;
        if (onep) {
            lw = wl + (size_t)l * 3145728;
            lb = bqkv + l * 1536;
        } else {
            cvt_layer<<<3072, 256, 0, stream>>>(wq + dd, wk + dd, wv + dd, wo + dd,
                                                w1 + fd, w2 + fd,
                                                bq + l * 512, bk + l * 512, bv + l * 512,
                                                wl, bqkv);
            lw = wl;
            lb = bqkv;
        }
        // QKV fused GEMM (V written transposed to vtg by epilogue)
        gemm_kernel<64, 128, false, false, true, true><<<dim3(12, 64), 256, 0, stream>>>(
            hb, lw, lb, nullptr, qkvb, vtg, NROWS, 1536, 512);

        attn_kernel<<<512, 256, 0, stream>>>(qkvb, vtg, mbias, ob);

        gemm_kernel<64, 64, false, true, false, false><<<dim3(8, 64), 256, 0, stream>>>(
            ob, lw + 786432, bo + l * 512, h, h2, nullptr, NROWS, 512, 512);
        ln_kernel<<<NROWS, 512, 0, stream>>>(h2, ln1g + l * 512, ln1b + l * 512, h, hb);

        gemm_kernel<64, 128, true, false, true, false><<<dim3(16, 64), 256, 0, stream>>>(
            hb, lw + 1048576, b1 + l * 2048, nullptr, fbuf, nullptr, NROWS, 2048, 512);
        gemm_kernel<64, 64, false, true, false, false><<<dim3(8, 64), 256, 0, stream>>>(
            fbuf, lw + 2097152, b2 + l * 512, h, h2, nullptr, NROWS, 512, 2048);
        ln_kernel<<<NROWS, 512, 0, stream>>>(h2, ln2g + l * 512, ln2b + l * 512, h, hb);
    }

    ln_kernel<<<NROWS, 512, 0, stream>>>(h, lnfg, lnfb, h, hb);
    gemm_kernel<64, 64, false, false, false, false><<<dim3(8, 64), 256, 0, stream>>>(
        hb, lmwb, nullptr, nullptr, d_out, nullptr, NROWS, 512, 512);
}

// Round 15
// 704.834 us; speedup vs baseline: 1.0940x; 1.0094x over previous
//
#include <hip/hip_runtime.h>
#include <math.h>

#define D_MODEL 512
#define NHEAD   8
#define DKH     64
#define NLAYER  6
#define FFDIM   2048
#define VOCAB   512
#define BB      4
#define SS      1024
#define NROWS   4096

typedef unsigned short ushort_t;
typedef short short8 __attribute__((ext_vector_type(8)));
typedef float f32x4  __attribute__((ext_vector_type(4)));

__device__ __forceinline__ float bf2f(ushort_t u) {
    union { float f; unsigned int i; } x; x.i = ((unsigned int)u) << 16; return x.f;
}
__device__ __forceinline__ ushort_t f2bf(float f) {
    union { float f; unsigned int i; } x; x.f = f;
    unsigned int r = x.i + 0x7FFFu + ((x.i >> 16) & 1u);
    return (ushort_t)(r >> 16);
}
__device__ __forceinline__ void gload_lds16(const void* g, void* l) {
    __builtin_amdgcn_global_load_lds(
        (const __attribute__((address_space(1))) void*)g,
        (__attribute__((address_space(3))) void*)l, 16, 0, 0);
}
__device__ __forceinline__ void block_barrier() {
    __builtin_amdgcn_s_barrier();
    __builtin_amdgcn_sched_barrier(0);
}

// ------------------------------------------------------------- weight convert
// One-shot: all 6 layers + lm_w + maskbias in ONE dispatch (18689 blocks).
// Per-layer layout: qkv 786432 | wo 262144 | w1 1048576 | w2 1048576
__global__ __launch_bounds__(256) void cvt_all(
    const float* __restrict__ wq, const float* __restrict__ wk, const float* __restrict__ wv,
    const float* __restrict__ wo, const float* __restrict__ w1, const float* __restrict__ w2,
    const float* __restrict__ bq, const float* __restrict__ bk, const float* __restrict__ bv,
    ushort_t* __restrict__ wl, float* __restrict__ bqkv,
    const float* __restrict__ lmw, ushort_t* __restrict__ lmwb,
    const int* __restrict__ am, float* __restrict__ mbias)
{
    const int bidx = blockIdx.x;
    const int tt = threadIdx.x;
    if (bidx < 18432) {
        int idx = bidx * 256 + tt;              // quad id, 4,718,592 total
        int e = idx * 4;
        int l = e / 3145728;
        int off = e - l * 3145728;
        float4 v;
        if (off < 786432) {
            if (off < 262144)       v = *(const float4*)(wq + l * 262144 + off);
            else if (off < 524288)  v = *(const float4*)(wk + l * 262144 + (off - 262144));
            else                    v = *(const float4*)(wv + l * 262144 + (off - 524288));
        } else if (off < 1048576)   v = *(const float4*)(wo + l * 262144 + (off - 786432));
        else if (off < 2097152)     v = *(const float4*)(w1 + l * 1048576 + (off - 1048576));
        else                        v = *(const float4*)(w2 + l * 1048576 + (off - 2097152));
        union { ushort_t u[4]; uint2 q; } pk;
        pk.u[0] = f2bf(v.x); pk.u[1] = f2bf(v.y); pk.u[2] = f2bf(v.z); pk.u[3] = f2bf(v.w);
        *(uint2*)(wl + e) = pk.q;
        if (idx < 2304) {           // 6 layers x 1536 qkv-bias floats
            int b4 = idx * 4;
            int bl = b4 / 1536;
            int r  = b4 - bl * 1536;
            float4 bv4;
            if (r < 512)       bv4 = *(const float4*)(bq + bl * 512 + r);
            else if (r < 1024) bv4 = *(const float4*)(bk + bl * 512 + (r - 512));
            else               bv4 = *(const float4*)(bv + bl * 512 + (r - 1024));
            *(float4*)(bqkv + b4) = bv4;
        }
    } else if (bidx < 18688) {
        // lm_w: 262144 floats = 65536 quads over 256 blocks
        int e = ((bidx - 18432) * 256 + tt) * 4;
        float4 v = *(const float4*)(lmw + e);
        union { ushort_t u[4]; uint2 q; } pk;
        pk.u[0] = f2bf(v.x); pk.u[1] = f2bf(v.y); pk.u[2] = f2bf(v.z); pk.u[3] = f2bf(v.w);
        *(uint2*)(lmwb + e) = pk.q;
    } else {
        // maskbias: 4096 ints, one block x 16 iters
#pragma unroll
        for (int i = 0; i < 16; ++i) {
            int j = i * 256 + tt;
            mbias[j] = am[j] ? 0.f : -1e9f;
        }
    }
}

// Per-layer fallback (if ws too small for one-shot)
__global__ __launch_bounds__(256) void cvt_layer(
    const float* __restrict__ wq, const float* __restrict__ wk, const float* __restrict__ wv,
    const float* __restrict__ wo, const float* __restrict__ w1, const float* __restrict__ w2,
    const float* __restrict__ bq, const float* __restrict__ bk, const float* __restrict__ bv,
    ushort_t* __restrict__ wl, float* __restrict__ bqkv)
{
    int idx = blockIdx.x * 256 + threadIdx.x;
    int e = idx * 4;
    float4 v;
    if (e < 786432) {
        if (e < 262144)       v = *(const float4*)(wq + e);
        else if (e < 524288)  v = *(const float4*)(wk + (e - 262144));
        else                  v = *(const float4*)(wv + (e - 524288));
    } else if (e < 1048576)   v = *(const float4*)(wo + (e - 786432));
    else if (e < 2097152)     v = *(const float4*)(w1 + (e - 1048576));
    else                      v = *(const float4*)(w2 + (e - 2097152));
    union { ushort_t u[4]; uint2 q; } pk;
    pk.u[0] = f2bf(v.x); pk.u[1] = f2bf(v.y); pk.u[2] = f2bf(v.z); pk.u[3] = f2bf(v.w);
    *(uint2*)(wl + e) = pk.q;
    if (idx < 384) {
        int b4 = idx * 4;
        float4 bv4;
        if (b4 < 512)       bv4 = *(const float4*)(bq + b4);
        else if (b4 < 1024) bv4 = *(const float4*)(bk + (b4 - 512));
        else                bv4 = *(const float4*)(bv + (b4 - 1024));
        *(float4*)(bqkv + b4) = bv4;
    }
}

__global__ __launch_bounds__(256) void cvt_simple(
    const float* __restrict__ src, ushort_t* __restrict__ dst)
{
    int e = (blockIdx.x * 256 + threadIdx.x) * 4;
    float4 v = *(const float4*)(src + e);
    union { ushort_t u[4]; uint2 q; } pk;
    pk.u[0] = f2bf(v.x); pk.u[1] = f2bf(v.y); pk.u[2] = f2bf(v.z); pk.u[3] = f2bf(v.w);
    *(uint2*)(dst + e) = pk.q;
}

__global__ __launch_bounds__(256) void maskbias_kernel(
    const int* __restrict__ am, float* __restrict__ mb)
{
    int i = blockIdx.x * 256 + threadIdx.x;
    if (i < NROWS) mb[i] = am[i] ? 0.f : -1e9f;
}

// ---------------------------------------------------------------- embedding
__global__ __launch_bounds__(512) void embed_kernel(
    const int* __restrict__ ids, const float* __restrict__ emb,
    float* __restrict__ xf, ushort_t* __restrict__ xb)
{
    int row = blockIdx.x;
    int d   = threadIdx.x;
    int s   = row & (SS - 1);
    int tok = ids[row];
    float div = expf(-(float)(d & ~1) * 0.0179889460390586f);
    float arg = (float)s * div;
    float pe  = (d & 1) ? cosf(arg) : sinf(arg);
    float v = emb[(size_t)tok * D_MODEL + d] * 22.62741699796952f + pe;
    xf[(size_t)row * D_MODEL + d] = v;
    xb[(size_t)row * D_MODEL + d] = f2bf(v);
}

// ---------------------------------------------------------------- layernorm
__global__ __launch_bounds__(512) void ln_kernel(
    const float* __restrict__ x, const float* __restrict__ g,
    const float* __restrict__ b, float* __restrict__ outf, ushort_t* __restrict__ outb)
{
    int row = blockIdx.x;
    int d   = threadIdx.x;
    int wave = d >> 6, lane = d & 63;
    __shared__ float red[8];

    float v = x[(size_t)row * D_MODEL + d];
    float s = v;
#pragma unroll
    for (int o = 32; o > 0; o >>= 1) s += __shfl_xor(s, o);
    if (lane == 0) red[wave] = s;
    __syncthreads();
    float tot = 0.f;
#pragma unroll
    for (int i = 0; i < 8; ++i) tot += red[i];
    float mu = tot * (1.0f / D_MODEL);
    float c  = v - mu;
    __syncthreads();
    float s2 = c * c;
#pragma unroll
    for (int o = 32; o > 0; o >>= 1) s2 += __shfl_xor(s2, o);
    if (lane == 0) red[wave] = s2;
    __syncthreads();
    float tot2 = 0.f;
#pragma unroll
    for (int i = 0; i < 8; ++i) tot2 += red[i];
    float var = tot2 * (1.0f / D_MODEL);
    float y = c * (1.0f / sqrtf(var + 1e-5f)) * g[d] + b[d];
    outf[(size_t)row * D_MODEL + d] = y;
    outb[(size_t)row * D_MODEL + d] = f2bf(y);
}

// ---------------------------------------------------------------- MFMA GEMM
// EXACT R9/R14 structure (verified best): single-buffer LDS, BK=64, XOR
// source-swizzled staging, __syncthreads loop, no setprio, no swizzle.
template<int BM, int BN, bool RELU, bool RES, bool OBF16, bool VT>
__global__ __launch_bounds__(256) void gemm_kernel(
    const ushort_t* __restrict__ A, const ushort_t* __restrict__ W,
    const float* __restrict__ bias, const float* __restrict__ res,
    void* __restrict__ out, ushort_t* __restrict__ vtg, int M, int N, int K)
{
    constexpr int WMT = BM / 2, WNT = BN / 2;
    constexpr int FM = WMT / 16, FN = WNT / 16;
    constexpr int ISSA = BM / 32, ISSB = BN / 32;
    __shared__ ushort_t As[BM * 64];
    __shared__ ushort_t Bs[BN * 64];

    const int t = threadIdx.x;
    const int w = t >> 6, lane = t & 63;
    const int wr = w >> 1, wc = w & 1;
    const int col0 = blockIdx.x * BN;
    const int row0 = blockIdx.y * BM;
    const int lrow = lane & 15, kg = lane >> 4;
    const int srow = t >> 3;                       // 0..31
    const int sk8  = (t & 7) ^ ((t >> 3) & 7);     // pre-swizzled source k8

    f32x4 acc[FM][FN];
#pragma unroll
    for (int m = 0; m < FM; ++m)
#pragma unroll
        for (int n = 0; n < FN; ++n) acc[m][n] = (f32x4){0.f, 0.f, 0.f, 0.f};

    for (int k0 = 0; k0 < K; k0 += 64) {
#pragma unroll
        for (int i = 0; i < ISSA; ++i)
            gload_lds16(A + (size_t)(row0 + i * 32 + srow) * K + k0 + sk8 * 8,
                        (char*)As + i * 4096 + t * 16);
#pragma unroll
        for (int i = 0; i < ISSB; ++i)
            gload_lds16(W + (size_t)(col0 + i * 32 + srow) * K + k0 + sk8 * 8,
                        (char*)Bs + i * 4096 + t * 16);
        __syncthreads();
#pragma unroll
        for (int kk = 0; kk < 2; ++kk) {
            short8 af[FM], bfv[FN];
#pragma unroll
            for (int m = 0; m < FM; ++m) {
                const int row = wr * WMT + m * 16 + lrow;
                af[m] = *(const short8*)&As[row * 64 + (((kk * 4 + kg) ^ (lrow & 7)) << 3)];
            }
#pragma unroll
            for (int n = 0; n < FN; ++n) {
                const int col = wc * WNT + n * 16 + lrow;
                bfv[n] = *(const short8*)&Bs[col * 64 + (((kk * 4 + kg) ^ (lrow & 7)) << 3)];
            }
#pragma unroll
            for (int m = 0; m < FM; ++m)
#pragma unroll
                for (int n = 0; n < FN; ++n)
                    acc[m][n] = __builtin_amdgcn_mfma_f32_16x16x32_bf16(
                        af[m], bfv[n], acc[m][n], 0, 0, 0);
        }
        __syncthreads();
    }

    const int lrow4 = (lane >> 4) * 4;
    const int lcol  = lane & 15;
#pragma unroll
    for (int m = 0; m < FM; ++m)
#pragma unroll
        for (int n = 0; n < FN; ++n) {
            const int col = col0 + wc * WNT + n * 16 + lcol;
            const float bv = bias ? bias[col] : 0.f;
            const int row_base = row0 + wr * WMT + m * 16 + lrow4;
            if (VT && col >= 1024) {
                const int vh = (col - 1024) >> 6;
                const int vd = (col - 1024) & 63;
                const int bq = row_base >> 10;
                const int s0 = row_base & 1023;
                union { ushort_t u[4]; uint2 q; } pk;
#pragma unroll
                for (int j = 0; j < 4; ++j) pk.u[j] = f2bf(acc[m][n][j] + bv);
                *(uint2*)(vtg + ((size_t)(bq * 8 + vh) * 64 + vd) * 1024 + s0) = pk.q;
            } else {
#pragma unroll
                for (int j = 0; j < 4; ++j) {
                    const int row = row_base + j;
                    float v = acc[m][n][j] + bv;
                    if (RES)  v += res[(size_t)row * N + col];
                    if (RELU) v = fmaxf(v, 0.f);
                    if (OBF16) ((ushort_t*)out)[(size_t)row * N + col] = f2bf(v);
                    else       ((float*)out)[(size_t)row * N + col] = v;
                }
            }
        }
}

// ---------------------------------------------------------------- attention
// R14 structure, deepened to a 3-buffer prefetch pipeline: prologue stages
// tiles 0,1; steady state issues STAGE(kt+2) then vmcnt(8) -- awaits only
// tile kt's 4 loads while 8 (tiles kt+1, kt+2) stay in flight across both
// barriers. LDS 48KB (still <=3 blocks/CU). Swapped-operand MFMA flash attn,
// zero-transport P handoff. K swizzle f(row)=(row>>3)&7; V f(row)=row&7.
__global__ __launch_bounds__(256) void attn_kernel(
    const ushort_t* __restrict__ qkv, const ushort_t* __restrict__ vtg,
    const float* __restrict__ mbias, ushort_t* __restrict__ o)
{
    __shared__ ushort_t Kl[3][64 * 64];   // [key][d]
    __shared__ ushort_t Vl[3][64 * 64];   // [d][key]

    const int t = threadIdx.x, w = t >> 6, l = t & 63;
    const int bid = blockIdx.x;
    const int qt = 15 - (bid >> 5);        // heavy tiles first
    const int bh = bid & 31, b = bh >> 3, h = bh & 7;
    const int q0 = qt * 64;
    const int lg = l >> 4, lr = l & 15;
    const int qi = q0 + w * 16 + lr;       // this lane's query

    const ushort_t* qrow = qkv + (size_t)(b * SS + qi) * 1536 + h * 64;
    const short8 qa0 = *(const short8*)(qrow + lg * 8);
    const short8 qa1 = *(const short8*)(qrow + 32 + lg * 8);

    float m_run = -1e30f, l_run = 0.f;
    f32x4 oacc[4];
#pragma unroll
    for (int nb = 0; nb < 4; ++nb) oacc[nb] = (f32x4){0.f, 0.f, 0.f, 0.f};

    const int krow = 32 * ((lr >> 1) & 1) + 8 * (lr >> 2) + (lr & 1);
    const ushort_t* qkvK = qkv + (size_t)(b * SS) * 1536 + 512 + h * 64;
    const ushort_t* vtgB = vtg + (size_t)bh * 64 * 1024;
    const float*    mb0  = mbias + b * SS + 8 * lg;

    const int sr0 = t >> 3, sc0 = t & 7;

    auto STAGE = [&](int buf, int kt) {
#pragma unroll
        for (int p = 0; p < 2; ++p) {
            const int row = p * 32 + sr0;
            const int ch  = sc0 ^ ((row >> 3) & 7);                 // K swizzle
            gload_lds16(qkvK + (size_t)(kt * 64 + row) * 1536 + ch * 8,
                        (char*)&Kl[buf][0] + (p * 256 + t) * 16);
        }
#pragma unroll
        for (int p = 0; p < 2; ++p) {
            const int row = p * 32 + sr0;
            const int ch  = sc0 ^ (row & 7);                        // V swizzle
            gload_lds16(vtgB + (size_t)row * 1024 + kt * 64 + ch * 8,
                        (char*)&Vl[buf][0] + (p * 256 + t) * 16);
        }
    };

    auto COMPUTE = [&](int buf, int kt) {
        const ushort_t* Kb = &Kl[buf][0];
        const ushort_t* Vb = &Vl[buf][0];
        short8 kf[8], vf[8];
#pragma unroll
        for (int nf = 0; nf < 4; ++nf) {
            const int row = 2 * nf + krow;
            const int sw  = (row >> 3) & 7;
            kf[2 * nf]     = *(const short8*)&Kb[row * 64 + ((lg ^ sw) << 3)];
            kf[2 * nf + 1] = *(const short8*)&Kb[row * 64 + (((4 + lg) ^ sw) << 3)];
        }
#pragma unroll
        for (int nb = 0; nb < 4; ++nb) {
            const int row = 16 * nb + lr;
            const int sw  = row & 7;
            vf[2 * nb]     = *(const short8*)&Vb[row * 64 + ((lg ^ sw) << 3)];
            vf[2 * nb + 1] = *(const short8*)&Vb[row * 64 + (((4 + lg) ^ sw) << 3)];
        }
        const float* mrow = mb0 + kt * 64;
        const float4 mA = *(const float4*)(mrow);
        const float4 mB = *(const float4*)(mrow + 4);
        const float4 mC = *(const float4*)(mrow + 32);
        const float4 mD = *(const float4*)(mrow + 36);
        // S = K * Q^T
        f32x4 s[4];
#pragma unroll
        for (int nf = 0; nf < 4; ++nf) {
            f32x4 a = (f32x4){0.f, 0.f, 0.f, 0.f};
            a = __builtin_amdgcn_mfma_f32_16x16x32_bf16(kf[2 * nf],     qa0, a, 0, 0, 0);
            a = __builtin_amdgcn_mfma_f32_16x16x32_bf16(kf[2 * nf + 1], qa1, a, 0, 0, 0);
            s[nf] = a;
        }
        const bool diag = (kt == qt);
        const int kbase = kt * 64 + 8 * lg;
#pragma unroll
        for (int nf = 0; nf < 4; ++nf) {
#pragma unroll
            for (int r = 0; r < 4; ++r) {
                const int e = r & 1, oo = (r >> 1) & 1;
                const int idx = 2 * nf + e;              // 0..7
                const float bias = oo ? (idx < 4 ? ((const float*)&mC)[idx] : ((const float*)&mD)[idx - 4])
                                      : (idx < 4 ? ((const float*)&mA)[idx] : ((const float*)&mB)[idx - 4]);
                float sv = s[nf][r] * 0.125f + bias;
                if (diag && (kbase + idx + 32 * oo) > qi) sv = -1e9f;
                s[nf][r] = sv;
            }
        }
        float pm[4];
#pragma unroll
        for (int nf = 0; nf < 4; ++nf)
            pm[nf] = fmaxf(fmaxf(s[nf][0], s[nf][1]), fmaxf(s[nf][2], s[nf][3]));
        float mx = fmaxf(fmaxf(pm[0], pm[1]), fmaxf(pm[2], pm[3]));
        mx = fmaxf(mx, __shfl_xor(mx, 16));
        mx = fmaxf(mx, __shfl_xor(mx, 32));
        const float mnew = fmaxf(m_run, mx);
        const float rs   = __expf(m_run - mnew);
        m_run = mnew;
        float ps[4];
#pragma unroll
        for (int nf = 0; nf < 4; ++nf) {
#pragma unroll
            for (int r = 0; r < 4; ++r) s[nf][r] = __expf(s[nf][r] - mnew);
            ps[nf] = (s[nf][0] + s[nf][1]) + (s[nf][2] + s[nf][3]);
        }
        float tsum = (ps[0] + ps[1]) + (ps[2] + ps[3]);
        tsum += __shfl_xor(tsum, 16);
        tsum += __shfl_xor(tsum, 32);
        l_run = l_run * rs + tsum;
#pragma unroll
        for (int nb = 0; nb < 4; ++nb)
#pragma unroll
            for (int r = 0; r < 4; ++r) oacc[nb][r] *= rs;
        union { unsigned u[4]; short8 s8; } pa0u, pa1u;
#pragma unroll
        for (int nf = 0; nf < 4; ++nf) {
            pa0u.u[nf] = ((unsigned)f2bf(s[nf][1]) << 16) | (unsigned)f2bf(s[nf][0]);
            pa1u.u[nf] = ((unsigned)f2bf(s[nf][3]) << 16) | (unsigned)f2bf(s[nf][2]);
        }
#pragma unroll
        for (int nb = 0; nb < 4; ++nb) {
            oacc[nb] = __builtin_amdgcn_mfma_f32_16x16x32_bf16(vf[2 * nb],     pa0u.s8, oacc[nb], 0, 0, 0);
            oacc[nb] = __builtin_amdgcn_mfma_f32_16x16x32_bf16(vf[2 * nb + 1], pa1u.s8, oacc[nb], 0, 0, 0);
        }
    };

    // 3-deep prefetch pipeline
    STAGE(0, 0);
    if (qt >= 1) STAGE(1, 1);
    int buf = 0;
    for (int kt = 0; kt <= qt; ++kt) {
        if (kt + 2 <= qt) {
            int nxt = buf + 2; if (nxt >= 3) nxt -= 3;
            STAGE(nxt, kt + 2);
            asm volatile("s_waitcnt vmcnt(8)" ::: "memory");   // await tile kt only
        } else if (kt + 1 <= qt) {
            asm volatile("s_waitcnt vmcnt(4)" ::: "memory");
        } else {
            asm volatile("s_waitcnt vmcnt(0)" ::: "memory");
        }
        block_barrier();                 // tile kt resident for all waves
        COMPUTE(buf, kt);
        block_barrier();                 // all reads of buf done before overwrite
        if (++buf == 3) buf = 0;
    }

    const float inv = 1.0f / l_run;
    ushort_t* orow = o + (size_t)(b * SS + qi) * 512 + h * 64;
#pragma unroll
    for (int nb = 0; nb < 4; ++nb) {
        union { ushort_t u[4]; uint2 q; } pk;
#pragma unroll
        for (int r = 0; r < 4; ++r) pk.u[r] = f2bf(oacc[nb][r] * inv);
        *(uint2*)(orow + nb * 16 + 4 * lg) = pk.q;
    }
}

// ---------------------------------------------------------------- launch
extern "C" void kernel_launch(void* const* d_in, const int* in_sizes, int n_in,
                              void* d_out, int out_size, void* d_ws, size_t ws_size,
                              hipStream_t stream)
{
    const int*   ids   = (const int*)d_in[0];
    const int*   am    = (const int*)d_in[1];
    const float* emb   = (const float*)d_in[2];
    const float* wq    = (const float*)d_in[3];
    const float* bq    = (const float*)d_in[4];
    const float* wk    = (const float*)d_in[5];
    const float* bk    = (const float*)d_in[6];
    const float* wv    = (const float*)d_in[7];
    const float* bv    = (const float*)d_in[8];
    const float* wo    = (const float*)d_in[9];
    const float* bo    = (const float*)d_in[10];
    const float* ln1g  = (const float*)d_in[11];
    const float* ln1b  = (const float*)d_in[12];
    const float* w1    = (const float*)d_in[13];
    const float* b1    = (const float*)d_in[14];
    const float* w2    = (const float*)d_in[15];
    const float* b2    = (const float*)d_in[16];
    const float* ln2g  = (const float*)d_in[17];
    const float* ln2b  = (const float*)d_in[18];
    const float* lnfg  = (const float*)d_in[19];
    const float* lnfb  = (const float*)d_in[20];
    const float* lmw   = (const float*)d_in[21];

    char* base = (char*)d_ws;
    float*    h    = (float*)(base);                    //  8 MB
    float*    h2   = (float*)(base + 8388608);          //  8 MB (attn: vtg 4MB)
    ushort_t* hb   = (ushort_t*)(base + 16777216);      //  4 MB
    ushort_t* act  = (ushort_t*)(base + 20971520);      // 16 MB shared
    ushort_t* qkvb = act;                               //   12 MB
    ushort_t* ob   = act + 6291456;                     //    4 MB
    ushort_t* fbuf = act;                               //   16 MB (after attn phase)
    ushort_t* vtg  = (ushort_t*)h2;                     //    4 MB, attn-phase only

    // weight-conversion scratch: one-shot if ws allows, else per-layer rotate
    const bool onep = ws_size >= (size_t)76100000;
    ushort_t* wl   = (ushort_t*)(base + 37748736);      // path A: 36 MB, path B: 6.3 MB
    float*    bqkv; ushort_t* lmwb; float* mbias;
    if (onep) {
        bqkv  = (float*)(base + 75497472);               // 36,864 B (6 x 1536)
        lmwb  = (ushort_t*)(base + 75534336);            // 524,288
        mbias = (float*)(base + 76058624);               // 16,384 -> end 76,075,008
    } else {
        bqkv  = (float*)(base + 44040192);
        lmwb  = (ushort_t*)(base + 44046336);
        mbias = (float*)(base + 44570624);
    }

    embed_kernel<<<NROWS, 512, 0, stream>>>(ids, emb, h, hb);
    if (onep) {
        cvt_all<<<18689, 256, 0, stream>>>(wq, wk, wv, wo, w1, w2, bq, bk, bv,
                                           wl, bqkv, lmw, lmwb, am, mbias);
    } else {
        cvt_simple<<<256, 256, 0, stream>>>(lmw, lmwb);
        maskbias_kernel<<<16, 256, 0, stream>>>(am, mbias);
    }

    for (int l = 0; l < NLAYER; ++l) {
        const size_t dd = (size_t)l * 262144;
        const size_t fd = (size_t)l * 1048576;
        ushort_t* lw; const float* lb;
        if (onep) {
            lw = wl + (size_t)l * 3145728;
            lb = bqkv + l * 1536;
        } else {
            cvt_layer<<<3072, 256, 0, stream>>>(wq + dd, wk + dd, wv + dd, wo + dd,
                                                w1 + fd, w2 + fd,
                                                bq + l * 512, bk + l * 512, bv + l * 512,
                                                wl, bqkv);
            lw = wl;
            lb = bqkv;
        }
        // QKV fused GEMM (V written transposed to vtg by epilogue)
        gemm_kernel<64, 128, false, false, true, true><<<dim3(12, 64), 256, 0, stream>>>(
            hb, lw, lb, nullptr, qkvb, vtg, NROWS, 1536, 512);

        attn_kernel<<<512, 256, 0, stream>>>(qkvb, vtg, mbias, ob);

        gemm_kernel<64, 64, false, true, false, false><<<dim3(8, 64), 256, 0, stream>>>(
            ob, lw + 786432, bo + l * 512, h, h2, nullptr, NROWS, 512, 512);
        ln_kernel<<<NROWS, 512, 0, stream>>>(h2, ln1g + l * 512, ln1b + l * 512, h, hb);

        gemm_kernel<64, 128, true, false, true, false><<<dim3(16, 64), 256, 0, stream>>>(
            hb, lw + 1048576, b1 + l * 2048, nullptr, fbuf, nullptr, NROWS, 2048, 512);
        gemm_kernel<64, 64, false, true, false, false><<<dim3(8, 64), 256, 0, stream>>>(
            fbuf, lw + 2097152, b2 + l * 512, h, h2, nullptr, NROWS, 512, 2048);
        ln_kernel<<<NROWS, 512, 0, stream>>>(h2, ln2g + l * 512, ln2b + l * 512, h, hb);
    }

    ln_kernel<<<NROWS, 512, 0, stream>>>(h, lnfg, lnfb, h, hb);
    gemm_kernel<64, 64, false, false, false, false><<<dim3(8, 64), 256, 0, stream>>>(
        hb, lmwb, nullptr, nullptr, d_out, nullptr, NROWS, 512, 512);
}

// Round 16
// 700.962 us; speedup vs baseline: 1.1001x; 1.0055x over previous
//
#include <hip/hip_runtime.h>
#include <math.h>

#define D_MODEL 512
#define NHEAD   8
#define DKH     64
#define NLAYER  6
#define FFDIM   2048
#define VOCAB   512
#define BB      4
#define SS      1024
#define NROWS   4096

typedef unsigned short ushort_t;
typedef short short8 __attribute__((ext_vector_type(8)));
typedef float f32x4  __attribute__((ext_vector_type(4)));

__device__ __forceinline__ float bf2f(ushort_t u) {
    union { float f; unsigned int i; } x; x.i = ((unsigned int)u) << 16; return x.f;
}
__device__ __forceinline__ ushort_t f2bf(float f) {
    union { float f; unsigned int i; } x; x.f = f;
    unsigned int r = x.i + 0x7FFFu + ((x.i >> 16) & 1u);
    return (ushort_t)(r >> 16);
}
__device__ __forceinline__ void gload_lds16(const void* g, void* l) {
    __builtin_amdgcn_global_load_lds(
        (const __attribute__((address_space(1))) void*)g,
        (__attribute__((address_space(3))) void*)l, 16, 0, 0);
}
template<int N> __device__ __forceinline__ void waitcnt_vm() {
    if constexpr (N == 0)      asm volatile("s_waitcnt vmcnt(0)" ::: "memory");
    else if constexpr (N == 4) asm volatile("s_waitcnt vmcnt(4)" ::: "memory");
    else if constexpr (N == 6) asm volatile("s_waitcnt vmcnt(6)" ::: "memory");
    else if constexpr (N == 8) asm volatile("s_waitcnt vmcnt(8)" ::: "memory");
    else if constexpr (N == 12) asm volatile("s_waitcnt vmcnt(12)" ::: "memory");
}
__device__ __forceinline__ void block_barrier() {
    __builtin_amdgcn_s_barrier();
    __builtin_amdgcn_sched_barrier(0);
}

// ------------------------------------------------------------- weight convert
// One-shot: all 6 layers + lm_w + maskbias in ONE dispatch (18689 blocks).
__global__ __launch_bounds__(256) void cvt_all(
    const float* __restrict__ wq, const float* __restrict__ wk, const float* __restrict__ wv,
    const float* __restrict__ wo, const float* __restrict__ w1, const float* __restrict__ w2,
    const float* __restrict__ bq, const float* __restrict__ bk, const float* __restrict__ bv,
    ushort_t* __restrict__ wl, float* __restrict__ bqkv,
    const float* __restrict__ lmw, ushort_t* __restrict__ lmwb,
    const int* __restrict__ am, float* __restrict__ mbias)
{
    const int bidx = blockIdx.x;
    const int tt = threadIdx.x;
    if (bidx < 18432) {
        int idx = bidx * 256 + tt;
        int e = idx * 4;
        int l = e / 3145728;
        int off = e - l * 3145728;
        float4 v;
        if (off < 786432) {
            if (off < 262144)       v = *(const float4*)(wq + l * 262144 + off);
            else if (off < 524288)  v = *(const float4*)(wk + l * 262144 + (off - 262144));
            else                    v = *(const float4*)(wv + l * 262144 + (off - 524288));
        } else if (off < 1048576)   v = *(const float4*)(wo + l * 262144 + (off - 786432));
        else if (off < 2097152)     v = *(const float4*)(w1 + l * 1048576 + (off - 1048576));
        else                        v = *(const float4*)(w2 + l * 1048576 + (off - 2097152));
        union { ushort_t u[4]; uint2 q; } pk;
        pk.u[0] = f2bf(v.x); pk.u[1] = f2bf(v.y); pk.u[2] = f2bf(v.z); pk.u[3] = f2bf(v.w);
        *(uint2*)(wl + e) = pk.q;
        if (idx < 2304) {
            int b4 = idx * 4;
            int bl = b4 / 1536;
            int r  = b4 - bl * 1536;
            float4 bv4;
            if (r < 512)       bv4 = *(const float4*)(bq + bl * 512 + r);
            else if (r < 1024) bv4 = *(const float4*)(bk + bl * 512 + (r - 512));
            else               bv4 = *(const float4*)(bv + bl * 512 + (r - 1024));
            *(float4*)(bqkv + b4) = bv4;
        }
    } else if (bidx < 18688) {
        int e = ((bidx - 18432) * 256 + tt) * 4;
        float4 v = *(const float4*)(lmw + e);
        union { ushort_t u[4]; uint2 q; } pk;
        pk.u[0] = f2bf(v.x); pk.u[1] = f2bf(v.y); pk.u[2] = f2bf(v.z); pk.u[3] = f2bf(v.w);
        *(uint2*)(lmwb + e) = pk.q;
    } else {
#pragma unroll
        for (int i = 0; i < 16; ++i) {
            int j = i * 256 + tt;
            mbias[j] = am[j] ? 0.f : -1e9f;
        }
    }
}

// Per-layer fallback (if ws too small for one-shot)
__global__ __launch_bounds__(256) void cvt_layer(
    const float* __restrict__ wq, const float* __restrict__ wk, const float* __restrict__ wv,
    const float* __restrict__ wo, const float* __restrict__ w1, const float* __restrict__ w2,
    const float* __restrict__ bq, const float* __restrict__ bk, const float* __restrict__ bv,
    ushort_t* __restrict__ wl, float* __restrict__ bqkv)
{
    int idx = blockIdx.x * 256 + threadIdx.x;
    int e = idx * 4;
    float4 v;
    if (e < 786432) {
        if (e < 262144)       v = *(const float4*)(wq + e);
        else if (e < 524288)  v = *(const float4*)(wk + (e - 262144));
        else                  v = *(const float4*)(wv + (e - 524288));
    } else if (e < 1048576)   v = *(const float4*)(wo + (e - 786432));
    else if (e < 2097152)     v = *(const float4*)(w1 + (e - 1048576));
    else                      v = *(const float4*)(w2 + (e - 2097152));
    union { ushort_t u[4]; uint2 q; } pk;
    pk.u[0] = f2bf(v.x); pk.u[1] = f2bf(v.y); pk.u[2] = f2bf(v.z); pk.u[3] = f2bf(v.w);
    *(uint2*)(wl + e) = pk.q;
    if (idx < 384) {
        int b4 = idx * 4;
        float4 bv4;
        if (b4 < 512)       bv4 = *(const float4*)(bq + b4);
        else if (b4 < 1024) bv4 = *(const float4*)(bk + (b4 - 512));
        else                bv4 = *(const float4*)(bv + (b4 - 1024));
        *(float4*)(bqkv + b4) = bv4;
    }
}

__global__ __launch_bounds__(256) void cvt_simple(
    const float* __restrict__ src, ushort_t* __restrict__ dst)
{
    int e = (blockIdx.x * 256 + threadIdx.x) * 4;
    float4 v = *(const float4*)(src + e);
    union { ushort_t u[4]; uint2 q; } pk;
    pk.u[0] = f2bf(v.x); pk.u[1] = f2bf(v.y); pk.u[2] = f2bf(v.z); pk.u[3] = f2bf(v.w);
    *(uint2*)(dst + e) = pk.q;
}

__global__ __launch_bounds__(256) void maskbias_kernel(
    const int* __restrict__ am, float* __restrict__ mb)
{
    int i = blockIdx.x * 256 + threadIdx.x;
    if (i < NROWS) mb[i] = am[i] ? 0.f : -1e9f;
}

// ---------------------------------------------------------------- embedding
__global__ __launch_bounds__(512) void embed_kernel(
    const int* __restrict__ ids, const float* __restrict__ emb,
    float* __restrict__ xf, ushort_t* __restrict__ xb)
{
    int row = blockIdx.x;
    int d   = threadIdx.x;
    int s   = row & (SS - 1);
    int tok = ids[row];
    float div = expf(-(float)(d & ~1) * 0.0179889460390586f);
    float arg = (float)s * div;
    float pe  = (d & 1) ? cosf(arg) : sinf(arg);
    float v = emb[(size_t)tok * D_MODEL + d] * 22.62741699796952f + pe;
    xf[(size_t)row * D_MODEL + d] = v;
    xb[(size_t)row * D_MODEL + d] = f2bf(v);
}

// ---------------------------------------------------------------- layernorm
__global__ __launch_bounds__(512) void ln_kernel(
    const float* __restrict__ x, const float* __restrict__ g,
    const float* __restrict__ b, float* __restrict__ outf, ushort_t* __restrict__ outb)
{
    int row = blockIdx.x;
    int d   = threadIdx.x;
    int wave = d >> 6, lane = d & 63;
    __shared__ float red[8];

    float v = x[(size_t)row * D_MODEL + d];
    float s = v;
#pragma unroll
    for (int o = 32; o > 0; o >>= 1) s += __shfl_xor(s, o);
    if (lane == 0) red[wave] = s;
    __syncthreads();
    float tot = 0.f;
#pragma unroll
    for (int i = 0; i < 8; ++i) tot += red[i];
    float mu = tot * (1.0f / D_MODEL);
    float c  = v - mu;
    __syncthreads();
    float s2 = c * c;
#pragma unroll
    for (int o = 32; o > 0; o >>= 1) s2 += __shfl_xor(s2, o);
    if (lane == 0) red[wave] = s2;
    __syncthreads();
    float tot2 = 0.f;
#pragma unroll
    for (int i = 0; i < 8; ++i) tot2 += red[i];
    float var = tot2 * (1.0f / D_MODEL);
    float y = c * (1.0f / sqrtf(var + 1e-5f)) * g[d] + b[d];
    outf[(size_t)row * D_MODEL + d] = y;
    outb[(size_t)row * D_MODEL + d] = f2bf(y);
}

// ---------------------------------------------------------------- MFMA GEMM
// DEPTH-selectable counted-vmcnt pipeline. Occupancy audit per launch:
//   QKV 64x128 grid 768 (3/CU): DEPTH=2 -> 48KB, 3x48=144<=160 OK
//   64x64 grids 512 (2/CU):     DEPTH=3 -> 48KB, 2x48= 96<=160 OK
//   FFN1 64x128 grid 1024 (4/CU): DEPTH=1 -> 24KB keeps 4/CU (dbuf would cost a block: R13 lesson)
// DEPTH>=2: STAGE(it+DEPTH-1) issued, then vmcnt((DEPTH-1)*NL) awaits only
// tile it's NL loads; later tiles stay in flight across both s_barriers.
template<int BM, int BN, int DEPTH, bool RELU, bool RES, bool OBF16, bool VT>
__global__ __launch_bounds__(256) void gemm_kernel(
    const ushort_t* __restrict__ A, const ushort_t* __restrict__ W,
    const float* __restrict__ bias, const float* __restrict__ res,
    void* __restrict__ out, ushort_t* __restrict__ vtg, int M, int N, int K)
{
    constexpr int WMT = BM / 2, WNT = BN / 2;
    constexpr int FM = WMT / 16, FN = WNT / 16;
    constexpr int ISSA = BM / 32, ISSB = BN / 32;
    constexpr int NL = ISSA + ISSB;
    __shared__ ushort_t As[DEPTH][BM * 64];
    __shared__ ushort_t Bs[DEPTH][BN * 64];

    const int t = threadIdx.x;
    const int w = t >> 6, lane = t & 63;
    const int wr = w >> 1, wc = w & 1;
    const int col0 = blockIdx.x * BN;
    const int row0 = blockIdx.y * BM;
    const int lrow = lane & 15, kg = lane >> 4;
    const int srow = t >> 3;                       // 0..31
    const int sk8  = (t & 7) ^ ((t >> 3) & 7);     // pre-swizzled source k8

    f32x4 acc[FM][FN];
#pragma unroll
    for (int m = 0; m < FM; ++m)
#pragma unroll
        for (int n = 0; n < FN; ++n) acc[m][n] = (f32x4){0.f, 0.f, 0.f, 0.f};

    auto STAGE = [&](int sb, int k0) {
#pragma unroll
        for (int i = 0; i < ISSA; ++i)
            gload_lds16(A + (size_t)(row0 + i * 32 + srow) * K + k0 + sk8 * 8,
                        (char*)&As[sb][0] + i * 4096 + t * 16);
#pragma unroll
        for (int i = 0; i < ISSB; ++i)
            gload_lds16(W + (size_t)(col0 + i * 32 + srow) * K + k0 + sk8 * 8,
                        (char*)&Bs[sb][0] + i * 4096 + t * 16);
    };

    const int NIT = K >> 6;
    STAGE(0, 0);
    if constexpr (DEPTH >= 3) { if (NIT > 1) STAGE(1, 64); }

    int buf = 0;
    for (int it = 0; it < NIT; ++it) {
        if constexpr (DEPTH == 1) {
            if (it > 0) STAGE(0, it * 64);
            waitcnt_vm<0>();
        } else if constexpr (DEPTH == 2) {
            if (it + 1 < NIT) { STAGE(buf ^ 1, (it + 1) * 64); waitcnt_vm<NL>(); }
            else              { waitcnt_vm<0>(); }
        } else {  // DEPTH == 3
            if (it + 2 < NIT) {
                int nxt = buf + 2; if (nxt >= 3) nxt -= 3;
                STAGE(nxt, (it + 2) * 64);
                waitcnt_vm<2 * NL>();
            } else if (it + 1 < NIT) { waitcnt_vm<NL>(); }
            else                     { waitcnt_vm<0>(); }
        }
        block_barrier();                 // tile `it` resident for all waves
#pragma unroll
        for (int kk = 0; kk < 2; ++kk) {
            short8 af[FM], bfv[FN];
#pragma unroll
            for (int m = 0; m < FM; ++m) {
                const int row = wr * WMT + m * 16 + lrow;
                af[m] = *(const short8*)&As[buf][row * 64 + (((kk * 4 + kg) ^ (lrow & 7)) << 3)];
            }
#pragma unroll
            for (int n = 0; n < FN; ++n) {
                const int col = wc * WNT + n * 16 + lrow;
                bfv[n] = *(const short8*)&Bs[buf][col * 64 + (((kk * 4 + kg) ^ (lrow & 7)) << 3)];
            }
#pragma unroll
            for (int m = 0; m < FM; ++m)
#pragma unroll
                for (int n = 0; n < FN; ++n)
                    acc[m][n] = __builtin_amdgcn_mfma_f32_16x16x32_bf16(
                        af[m], bfv[n], acc[m][n], 0, 0, 0);
        }
        block_barrier();                 // all reads of buf done before overwrite
        if constexpr (DEPTH == 2) buf ^= 1;
        else if constexpr (DEPTH == 3) { if (++buf == 3) buf = 0; }
    }

    const int lrow4 = (lane >> 4) * 4;
    const int lcol  = lane & 15;
#pragma unroll
    for (int m = 0; m < FM; ++m)
#pragma unroll
        for (int n = 0; n < FN; ++n) {
            const int col = col0 + wc * WNT + n * 16 + lcol;
            const float bv = bias ? bias[col] : 0.f;
            const int row_base = row0 + wr * WMT + m * 16 + lrow4;
            if (VT && col >= 1024) {
                const int vh = (col - 1024) >> 6;
                const int vd = (col - 1024) & 63;
                const int bq = row_base >> 10;
                const int s0 = row_base & 1023;
                union { ushort_t u[4]; uint2 q; } pk;
#pragma unroll
                for (int j = 0; j < 4; ++j) pk.u[j] = f2bf(acc[m][n][j] + bv);
                *(uint2*)(vtg + ((size_t)(bq * 8 + vh) * 64 + vd) * 1024 + s0) = pk.q;
            } else {
#pragma unroll
                for (int j = 0; j < 4; ++j) {
                    const int row = row_base + j;
                    float v = acc[m][n][j] + bv;
                    if (RES)  v += res[(size_t)row * N + col];
                    if (RELU) v = fmaxf(v, 0.f);
                    if (OBF16) ((ushort_t*)out)[(size_t)row * N + col] = f2bf(v);
                    else       ((float*)out)[(size_t)row * N + col] = v;
                }
            }
        }
}

// ---------------------------------------------------------------- attention
// R15 exact: 3-buffer counted-vmcnt prefetch (vmcnt(8) steady state), swapped-
// operand MFMA flash attention, zero-transport P handoff, LDS-staged K/V.
// K swizzle f(row)=(row>>3)&7; V swizzle f(row)=row&7.
__global__ __launch_bounds__(256) void attn_kernel(
    const ushort_t* __restrict__ qkv, const ushort_t* __restrict__ vtg,
    const float* __restrict__ mbias, ushort_t* __restrict__ o)
{
    __shared__ ushort_t Kl[3][64 * 64];   // [key][d]
    __shared__ ushort_t Vl[3][64 * 64];   // [d][key]

    const int t = threadIdx.x, w = t >> 6, l = t & 63;
    const int bid = blockIdx.x;
    const int qt = 15 - (bid >> 5);        // heavy tiles first
    const int bh = bid & 31, b = bh >> 3, h = bh & 7;
    const int q0 = qt * 64;
    const int lg = l >> 4, lr = l & 15;
    const int qi = q0 + w * 16 + lr;       // this lane's query

    const ushort_t* qrow = qkv + (size_t)(b * SS + qi) * 1536 + h * 64;
    const short8 qa0 = *(const short8*)(qrow + lg * 8);
    const short8 qa1 = *(const short8*)(qrow + 32 + lg * 8);

    float m_run = -1e30f, l_run = 0.f;
    f32x4 oacc[4];
#pragma unroll
    for (int nb = 0; nb < 4; ++nb) oacc[nb] = (f32x4){0.f, 0.f, 0.f, 0.f};

    const int krow = 32 * ((lr >> 1) & 1) + 8 * (lr >> 2) + (lr & 1);
    const ushort_t* qkvK = qkv + (size_t)(b * SS) * 1536 + 512 + h * 64;
    const ushort_t* vtgB = vtg + (size_t)bh * 64 * 1024;
    const float*    mb0  = mbias + b * SS + 8 * lg;

    const int sr0 = t >> 3, sc0 = t & 7;

    auto STAGE = [&](int buf, int kt) {
#pragma unroll
        for (int p = 0; p < 2; ++p) {
            const int row = p * 32 + sr0;
            const int ch  = sc0 ^ ((row >> 3) & 7);                 // K swizzle
            gload_lds16(qkvK + (size_t)(kt * 64 + row) * 1536 + ch * 8,
                        (char*)&Kl[buf][0] + (p * 256 + t) * 16);
        }
#pragma unroll
        for (int p = 0; p < 2; ++p) {
            const int row = p * 32 + sr0;
            const int ch  = sc0 ^ (row & 7);                        // V swizzle
            gload_lds16(vtgB + (size_t)row * 1024 + kt * 64 + ch * 8,
                        (char*)&Vl[buf][0] + (p * 256 + t) * 16);
        }
    };

    auto COMPUTE = [&](int buf, int kt) {
        const ushort_t* Kb = &Kl[buf][0];
        const ushort_t* Vb = &Vl[buf][0];
        short8 kf[8], vf[8];
#pragma unroll
        for (int nf = 0; nf < 4; ++nf) {
            const int row = 2 * nf + krow;
            const int sw  = (row >> 3) & 7;
            kf[2 * nf]     = *(const short8*)&Kb[row * 64 + ((lg ^ sw) << 3)];
            kf[2 * nf + 1] = *(const short8*)&Kb[row * 64 + (((4 + lg) ^ sw) << 3)];
        }
#pragma unroll
        for (int nb = 0; nb < 4; ++nb) {
            const int row = 16 * nb + lr;
            const int sw  = row & 7;
            vf[2 * nb]     = *(const short8*)&Vb[row * 64 + ((lg ^ sw) << 3)];
            vf[2 * nb + 1] = *(const short8*)&Vb[row * 64 + (((4 + lg) ^ sw) << 3)];
        }
        const float* mrow = mb0 + kt * 64;
        const float4 mA = *(const float4*)(mrow);
        const float4 mB = *(const float4*)(mrow + 4);
        const float4 mC = *(const float4*)(mrow + 32);
        const float4 mD = *(const float4*)(mrow + 36);
        // S = K * Q^T
        f32x4 s[4];
#pragma unroll
        for (int nf = 0; nf < 4; ++nf) {
            f32x4 a = (f32x4){0.f, 0.f, 0.f, 0.f};
            a = __builtin_amdgcn_mfma_f32_16x16x32_bf16(kf[2 * nf],     qa0, a, 0, 0, 0);
            a = __builtin_amdgcn_mfma_f32_16x16x32_bf16(kf[2 * nf + 1], qa1, a, 0, 0, 0);
            s[nf] = a;
        }
        const bool diag = (kt == qt);
        const int kbase = kt * 64 + 8 * lg;
#pragma unroll
        for (int nf = 0; nf < 4; ++nf) {
#pragma unroll
            for (int r = 0; r < 4; ++r) {
                const int e = r & 1, oo = (r >> 1) & 1;
                const int idx = 2 * nf + e;              // 0..7
                const float bias = oo ? (idx < 4 ? ((const float*)&mC)[idx] : ((const float*)&mD)[idx - 4])
                                      : (idx < 4 ? ((const float*)&mA)[idx] : ((const float*)&mB)[idx - 4]);
                float sv = s[nf][r] * 0.125f + bias;
                if (diag && (kbase + idx + 32 * oo) > qi) sv = -1e9f;
                s[nf][r] = sv;
            }
        }
        float pm[4];
#pragma unroll
        for (int nf = 0; nf < 4; ++nf)
            pm[nf] = fmaxf(fmaxf(s[nf][0], s[nf][1]), fmaxf(s[nf][2], s[nf][3]));
        float mx = fmaxf(fmaxf(pm[0], pm[1]), fmaxf(pm[2], pm[3]));
        mx = fmaxf(mx, __shfl_xor(mx, 16));
        mx = fmaxf(mx, __shfl_xor(mx, 32));
        const float mnew = fmaxf(m_run, mx);
        const float rs   = __expf(m_run - mnew);
        m_run = mnew;
        float ps[4];
#pragma unroll
        for (int nf = 0; nf < 4; ++nf) {
#pragma unroll
            for (int r = 0; r < 4; ++r) s[nf][r] = __expf(s[nf][r] - mnew);
            ps[nf] = (s[nf][0] + s[nf][1]) + (s[nf][2] + s[nf][3]);
        }
        float tsum = (ps[0] + ps[1]) + (ps[2] + ps[3]);
        tsum += __shfl_xor(tsum, 16);
        tsum += __shfl_xor(tsum, 32);
        l_run = l_run * rs + tsum;
#pragma unroll
        for (int nb = 0; nb < 4; ++nb)
#pragma unroll
            for (int r = 0; r < 4; ++r) oacc[nb][r] *= rs;
        union { unsigned u[4]; short8 s8; } pa0u, pa1u;
#pragma unroll
        for (int nf = 0; nf < 4; ++nf) {
            pa0u.u[nf] = ((unsigned)f2bf(s[nf][1]) << 16) | (unsigned)f2bf(s[nf][0]);
            pa1u.u[nf] = ((unsigned)f2bf(s[nf][3]) << 16) | (unsigned)f2bf(s[nf][2]);
        }
#pragma unroll
        for (int nb = 0; nb < 4; ++nb) {
            oacc[nb] = __builtin_amdgcn_mfma_f32_16x16x32_bf16(vf[2 * nb],     pa0u.s8, oacc[nb], 0, 0, 0);
            oacc[nb] = __builtin_amdgcn_mfma_f32_16x16x32_bf16(vf[2 * nb + 1], pa1u.s8, oacc[nb], 0, 0, 0);
        }
    };

    // 3-deep prefetch pipeline
    STAGE(0, 0);
    if (qt >= 1) STAGE(1, 1);
    int buf = 0;
    for (int kt = 0; kt <= qt; ++kt) {
        if (kt + 2 <= qt) {
            int nxt = buf + 2; if (nxt >= 3) nxt -= 3;
            STAGE(nxt, kt + 2);
            asm volatile("s_waitcnt vmcnt(8)" ::: "memory");   // await tile kt only
        } else if (kt + 1 <= qt) {
            asm volatile("s_waitcnt vmcnt(4)" ::: "memory");
        } else {
            asm volatile("s_waitcnt vmcnt(0)" ::: "memory");
        }
        block_barrier();                 // tile kt resident for all waves
        COMPUTE(buf, kt);
        block_barrier();                 // all reads of buf done before overwrite
        if (++buf == 3) buf = 0;
    }

    const float inv = 1.0f / l_run;
    ushort_t* orow = o + (size_t)(b * SS + qi) * 512 + h * 64;
#pragma unroll
    for (int nb = 0; nb < 4; ++nb) {
        union { ushort_t u[4]; uint2 q; } pk;
#pragma unroll
        for (int r = 0; r < 4; ++r) pk.u[r] = f2bf(oacc[nb][r] * inv);
        *(uint2*)(orow + nb * 16 + 4 * lg) = pk.q;
    }
}

// ---------------------------------------------------------------- launch
extern "C" void kernel_launch(void* const* d_in, const int* in_sizes, int n_in,
                              void* d_out, int out_size, void* d_ws, size_t ws_size,
                              hipStream_t stream)
{
    const int*   ids   = (const int*)d_in[0];
    const int*   am    = (const int*)d_in[1];
    const float* emb   = (const float*)d_in[2];
    const float* wq    = (const float*)d_in[3];
    const float* bq    = (const float*)d_in[4];
    const float* wk    = (const float*)d_in[5];
    const float* bk    = (const float*)d_in[6];
    const float* wv    = (const float*)d_in[7];
    const float* bv    = (const float*)d_in[8];
    const float* wo    = (const float*)d_in[9];
    const float* bo    = (const float*)d_in[10];
    const float* ln1g  = (const float*)d_in[11];
    const float* ln1b  = (const float*)d_in[12];
    const float* w1    = (const float*)d_in[13];
    const float* b1    = (const float*)d_in[14];
    const float* w2    = (const float*)d_in[15];
    const float* b2    = (const float*)d_in[16];
    const float* ln2g  = (const float*)d_in[17];
    const float* ln2b  = (const float*)d_in[18];
    const float* lnfg  = (const float*)d_in[19];
    const float* lnfb  = (const float*)d_in[20];
    const float* lmw   = (const float*)d_in[21];

    char* base = (char*)d_ws;
    float*    h    = (float*)(base);                    //  8 MB
    float*    h2   = (float*)(base + 8388608);          //  8 MB (attn: vtg 4MB)
    ushort_t* hb   = (ushort_t*)(base + 16777216);      //  4 MB
    ushort_t* act  = (ushort_t*)(base + 20971520);      // 16 MB shared
    ushort_t* qkvb = act;                               //   12 MB
    ushort_t* ob   = act + 6291456;                     //    4 MB
    ushort_t* fbuf = act;                               //   16 MB (after attn phase)
    ushort_t* vtg  = (ushort_t*)h2;                     //    4 MB, attn-phase only

    // weight-conversion scratch: one-shot if ws allows, else per-layer rotate
    const bool onep = ws_size >= (size_t)76100000;
    ushort_t* wl   = (ushort_t*)(base + 37748736);      // path A: 36 MB, path B: 6.3 MB
    float*    bqkv; ushort_t* lmwb; float* mbias;
    if (onep) {
        bqkv  = (float*)(base + 75497472);               // 36,864 B (6 x 1536)
        lmwb  = (ushort_t*)(base + 75534336);            // 524,288
        mbias = (float*)(base + 76058624);               // 16,384 -> end 76,075,008
    } else {
        bqkv  = (float*)(base + 44040192);
        lmwb  = (ushort_t*)(base + 44046336);
        mbias = (float*)(base + 44570624);
    }

    embed_kernel<<<NROWS, 512, 0, stream>>>(ids, emb, h, hb);
    if (onep) {
        cvt_all<<<18689, 256, 0, stream>>>(wq, wk, wv, wo, w1, w2, bq, bk, bv,
                                           wl, bqkv, lmw, lmwb, am, mbias);
    } else {
        cvt_simple<<<256, 256, 0, stream>>>(lmw, lmwb);
        maskbias_kernel<<<16, 256, 0, stream>>>(am, mbias);
    }

    for (int l = 0; l < NLAYER; ++l) {
        const size_t dd = (size_t)l * 262144;
        const size_t fd = (size_t)l * 1048576;
        ushort_t* lw; const float* lb;
        if (onep) {
            lw = wl + (size_t)l * 3145728;
            lb = bqkv + l * 1536;
        } else {
            cvt_layer<<<3072, 256, 0, stream>>>(wq + dd, wk + dd, wv + dd, wo + dd,
                                                w1 + fd, w2 + fd,
                                                bq + l * 512, bk + l * 512, bv + l * 512,
                                                wl, bqkv);
            lw = wl;
            lb = bqkv;
        }
        // QKV fused GEMM, DEPTH=2 (V written transposed to vtg by epilogue)
        gemm_kernel<64, 128, 2, false, false, true, true><<<dim3(12, 64), 256, 0, stream>>>(
            hb, lw, lb, nullptr, qkvb, vtg, NROWS, 1536, 512);

        attn_kernel<<<512, 256, 0, stream>>>(qkvb, vtg, mbias, ob);

        gemm_kernel<64, 64, 3, false, true, false, false><<<dim3(8, 64), 256, 0, stream>>>(
            ob, lw + 786432, bo + l * 512, h, h2, nullptr, NROWS, 512, 512);
        ln_kernel<<<NROWS, 512, 0, stream>>>(h2, ln1g + l * 512, ln1b + l * 512, h, hb);

        gemm_kernel<64, 128, 1, true, false, true, false><<<dim3(16, 64), 256, 0, stream>>>(
            hb, lw + 1048576, b1 + l * 2048, nullptr, fbuf, nullptr, NROWS, 2048, 512);
        gemm_kernel<64, 64, 3, false, true, false, false><<<dim3(8, 64), 256, 0, stream>>>(
            fbuf, lw + 2097152, b2 + l * 512, h, h2, nullptr, NROWS, 512, 2048);
        ln_kernel<<<NROWS, 512, 0, stream>>>(h2, ln2g + l * 512, ln2b + l * 512, h, hb);
    }

    ln_kernel<<<NROWS, 512, 0, stream>>>(h, lnfg, lnfb, h, hb);
    gemm_kernel<64, 64, 3, false, false, false, false><<<dim3(8, 64), 256, 0, stream>>>(
        hb, lmwb, nullptr, nullptr, d_out, nullptr, NROWS, 512, 512);
}

// Round 17
// 685.459 us; speedup vs baseline: 1.1249x; 1.0226x over previous
//
#include <hip/hip_runtime.h>
#include <math.h>

#define D_MODEL 512
#define NHEAD   8
#define DKH     64
#define NLAYER  6
#define FFDIM   2048
#define VOCAB   512
#define BB      4
#define SS      1024
#define NROWS   4096

typedef unsigned short ushort_t;
typedef short short8 __attribute__((ext_vector_type(8)));
typedef float f32x4  __attribute__((ext_vector_type(4)));

__device__ __forceinline__ float bf2f(ushort_t u) {
    union { float f; unsigned int i; } x; x.i = ((unsigned int)u) << 16; return x.f;
}
__device__ __forceinline__ ushort_t f2bf(float f) {
    union { float f; unsigned int i; } x; x.f = f;
    unsigned int r = x.i + 0x7FFFu + ((x.i >> 16) & 1u);
    return (ushort_t)(r >> 16);
}
__device__ __forceinline__ void gload_lds16(const void* g, void* l) {
    __builtin_amdgcn_global_load_lds(
        (const __attribute__((address_space(1))) void*)g,
        (__attribute__((address_space(3))) void*)l, 16, 0, 0);
}
template<int N> __device__ __forceinline__ void waitcnt_vm() {
    if constexpr (N == 0)      asm volatile("s_waitcnt vmcnt(0)" ::: "memory");
    else if constexpr (N == 3) asm volatile("s_waitcnt vmcnt(3)" ::: "memory");
    else if constexpr (N == 4) asm volatile("s_waitcnt vmcnt(4)" ::: "memory");
    else if constexpr (N == 6) asm volatile("s_waitcnt vmcnt(6)" ::: "memory");
    else if constexpr (N == 8) asm volatile("s_waitcnt vmcnt(8)" ::: "memory");
    else if constexpr (N == 12) asm volatile("s_waitcnt vmcnt(12)" ::: "memory");
}
__device__ __forceinline__ void block_barrier() {
    __builtin_amdgcn_s_barrier();
    __builtin_amdgcn_sched_barrier(0);
}

// ------------------------------------------------------------- weight convert
// One-shot: all 6 layers + lm_w + maskbias in ONE dispatch (18689 blocks).
__global__ __launch_bounds__(256) void cvt_all(
    const float* __restrict__ wq, const float* __restrict__ wk, const float* __restrict__ wv,
    const float* __restrict__ wo, const float* __restrict__ w1, const float* __restrict__ w2,
    const float* __restrict__ bq, const float* __restrict__ bk, const float* __restrict__ bv,
    ushort_t* __restrict__ wl, float* __restrict__ bqkv,
    const float* __restrict__ lmw, ushort_t* __restrict__ lmwb,
    const int* __restrict__ am, float* __restrict__ mbias)
{
    const int bidx = blockIdx.x;
    const int tt = threadIdx.x;
    if (bidx < 18432) {
        int idx = bidx * 256 + tt;
        int e = idx * 4;
        int l = e / 3145728;
        int off = e - l * 3145728;
        float4 v;
        if (off < 786432) {
            if (off < 262144)       v = *(const float4*)(wq + l * 262144 + off);
            else if (off < 524288)  v = *(const float4*)(wk + l * 262144 + (off - 262144));
            else                    v = *(const float4*)(wv + l * 262144 + (off - 524288));
        } else if (off < 1048576)   v = *(const float4*)(wo + l * 262144 + (off - 786432));
        else if (off < 2097152)     v = *(const float4*)(w1 + l * 1048576 + (off - 1048576));
        else                        v = *(const float4*)(w2 + l * 1048576 + (off - 2097152));
        union { ushort_t u[4]; uint2 q; } pk;
        pk.u[0] = f2bf(v.x); pk.u[1] = f2bf(v.y); pk.u[2] = f2bf(v.z); pk.u[3] = f2bf(v.w);
        *(uint2*)(wl + e) = pk.q;
        if (idx < 2304) {
            int b4 = idx * 4;
            int bl = b4 / 1536;
            int r  = b4 - bl * 1536;
            float4 bv4;
            if (r < 512)       bv4 = *(const float4*)(bq + bl * 512 + r);
            else if (r < 1024) bv4 = *(const float4*)(bk + bl * 512 + (r - 512));
            else               bv4 = *(const float4*)(bv + bl * 512 + (r - 1024));
            *(float4*)(bqkv + b4) = bv4;
        }
    } else if (bidx < 18688) {
        int e = ((bidx - 18432) * 256 + tt) * 4;
        float4 v = *(const float4*)(lmw + e);
        union { ushort_t u[4]; uint2 q; } pk;
        pk.u[0] = f2bf(v.x); pk.u[1] = f2bf(v.y); pk.u[2] = f2bf(v.z); pk.u[3] = f2bf(v.w);
        *(uint2*)(lmwb + e) = pk.q;
    } else {
#pragma unroll
        for (int i = 0; i < 16; ++i) {
            int j = i * 256 + tt;
            mbias[j] = am[j] ? 0.f : -1e9f;
        }
    }
}

// Per-layer fallback (if ws too small for one-shot)
__global__ __launch_bounds__(256) void cvt_layer(
    const float* __restrict__ wq, const float* __restrict__ wk, const float* __restrict__ wv,
    const float* __restrict__ wo, const float* __restrict__ w1, const float* __restrict__ w2,
    const float* __restrict__ bq, const float* __restrict__ bk, const float* __restrict__ bv,
    ushort_t* __restrict__ wl, float* __restrict__ bqkv)
{
    int idx = blockIdx.x * 256 + threadIdx.x;
    int e = idx * 4;
    float4 v;
    if (e < 786432) {
        if (e < 262144)       v = *(const float4*)(wq + e);
        else if (e < 524288)  v = *(const float4*)(wk + (e - 262144));
        else                  v = *(const float4*)(wv + (e - 524288));
    } else if (e < 1048576)   v = *(const float4*)(wo + (e - 786432));
    else if (e < 2097152)     v = *(const float4*)(w1 + (e - 1048576));
    else                      v = *(const float4*)(w2 + (e - 2097152));
    union { ushort_t u[4]; uint2 q; } pk;
    pk.u[0] = f2bf(v.x); pk.u[1] = f2bf(v.y); pk.u[2] = f2bf(v.z); pk.u[3] = f2bf(v.w);
    *(uint2*)(wl + e) = pk.q;
    if (idx < 384) {
        int b4 = idx * 4;
        float4 bv4;
        if (b4 < 512)       bv4 = *(const float4*)(bq + b4);
        else if (b4 < 1024) bv4 = *(const float4*)(bk + (b4 - 512));
        else                bv4 = *(const float4*)(bv + (b4 - 1024));
        *(float4*)(bqkv + b4) = bv4;
    }
}

__global__ __launch_bounds__(256) void cvt_simple(
    const float* __restrict__ src, ushort_t* __restrict__ dst)
{
    int e = (blockIdx.x * 256 + threadIdx.x) * 4;
    float4 v = *(const float4*)(src + e);
    union { ushort_t u[4]; uint2 q; } pk;
    pk.u[0] = f2bf(v.x); pk.u[1] = f2bf(v.y); pk.u[2] = f2bf(v.z); pk.u[3] = f2bf(v.w);
    *(uint2*)(dst + e) = pk.q;
}

__global__ __launch_bounds__(256) void maskbias_kernel(
    const int* __restrict__ am, float* __restrict__ mb)
{
    int i = blockIdx.x * 256 + threadIdx.x;
    if (i < NROWS) mb[i] = am[i] ? 0.f : -1e9f;
}

// ---------------------------------------------------------------- embedding
__global__ __launch_bounds__(512) void embed_kernel(
    const int* __restrict__ ids, const float* __restrict__ emb,
    float* __restrict__ xf, ushort_t* __restrict__ xb)
{
    int row = blockIdx.x;
    int d   = threadIdx.x;
    int s   = row & (SS - 1);
    int tok = ids[row];
    float div = expf(-(float)(d & ~1) * 0.0179889460390586f);
    float arg = (float)s * div;
    float pe  = (d & 1) ? cosf(arg) : sinf(arg);
    float v = emb[(size_t)tok * D_MODEL + d] * 22.62741699796952f + pe;
    xf[(size_t)row * D_MODEL + d] = v;
    xb[(size_t)row * D_MODEL + d] = f2bf(v);
}

// ---------------------------------------------------------------- layernorm
__global__ __launch_bounds__(512) void ln_kernel(
    const float* __restrict__ x, const float* __restrict__ g,
    const float* __restrict__ b, float* __restrict__ outf, ushort_t* __restrict__ outb)
{
    int row = blockIdx.x;
    int d   = threadIdx.x;
    int wave = d >> 6, lane = d & 63;
    __shared__ float red[8];

    float v = x[(size_t)row * D_MODEL + d];
    float s = v;
#pragma unroll
    for (int o = 32; o > 0; o >>= 1) s += __shfl_xor(s, o);
    if (lane == 0) red[wave] = s;
    __syncthreads();
    float tot = 0.f;
#pragma unroll
    for (int i = 0; i < 8; ++i) tot += red[i];
    float mu = tot * (1.0f / D_MODEL);
    float c  = v - mu;
    __syncthreads();
    float s2 = c * c;
#pragma unroll
    for (int o = 32; o > 0; o >>= 1) s2 += __shfl_xor(s2, o);
    if (lane == 0) red[wave] = s2;
    __syncthreads();
    float tot2 = 0.f;
#pragma unroll
    for (int i = 0; i < 8; ++i) tot2 += red[i];
    float var = tot2 * (1.0f / D_MODEL);
    float y = c * (1.0f / sqrtf(var + 1e-5f)) * g[d] + b[d];
    outf[(size_t)row * D_MODEL + d] = y;
    outb[(size_t)row * D_MODEL + d] = f2bf(y);
}

// ---------------------------------------------------------------- MFMA GEMM
// DEPTH-selectable counted-vmcnt pipeline. Occupancy audit per launch:
//   QKV 64x128 grid 768 (3/CU): DEPTH=2, 48KB (3x48=144<=160 OK)
//   narrow 32x64 grid 1024 (4/CU): DEPTH=3, 36KB (4x36=144<=160 OK)  [R17: was 64x64/2-per-CU]
//   FFN1 64x128 grid 1024 (4/CU): DEPTH=1, 24KB keeps 4/CU (R13 lesson)
template<int BM, int BN, int DEPTH, bool RELU, bool RES, bool OBF16, bool VT>
__global__ __launch_bounds__(256) void gemm_kernel(
    const ushort_t* __restrict__ A, const ushort_t* __restrict__ W,
    const float* __restrict__ bias, const float* __restrict__ res,
    void* __restrict__ out, ushort_t* __restrict__ vtg, int M, int N, int K)
{
    constexpr int WMT = BM / 2, WNT = BN / 2;
    constexpr int FM = WMT / 16, FN = WNT / 16;
    constexpr int ISSA = BM / 32, ISSB = BN / 32;
    constexpr int NL = ISSA + ISSB;
    __shared__ ushort_t As[DEPTH][BM * 64];
    __shared__ ushort_t Bs[DEPTH][BN * 64];

    const int t = threadIdx.x;
    const int w = t >> 6, lane = t & 63;
    const int wr = w >> 1, wc = w & 1;
    const int col0 = blockIdx.x * BN;
    const int row0 = blockIdx.y * BM;
    const int lrow = lane & 15, kg = lane >> 4;
    const int srow = t >> 3;                       // 0..31
    const int sk8  = (t & 7) ^ ((t >> 3) & 7);     // pre-swizzled source k8

    f32x4 acc[FM][FN];
#pragma unroll
    for (int m = 0; m < FM; ++m)
#pragma unroll
        for (int n = 0; n < FN; ++n) acc[m][n] = (f32x4){0.f, 0.f, 0.f, 0.f};

    auto STAGE = [&](int sb, int k0) {
#pragma unroll
        for (int i = 0; i < ISSA; ++i)
            gload_lds16(A + (size_t)(row0 + i * 32 + srow) * K + k0 + sk8 * 8,
                        (char*)&As[sb][0] + i * 4096 + t * 16);
#pragma unroll
        for (int i = 0; i < ISSB; ++i)
            gload_lds16(W + (size_t)(col0 + i * 32 + srow) * K + k0 + sk8 * 8,
                        (char*)&Bs[sb][0] + i * 4096 + t * 16);
    };

    const int NIT = K >> 6;
    STAGE(0, 0);
    if constexpr (DEPTH >= 3) { if (NIT > 1) STAGE(1, 64); }

    int buf = 0;
    for (int it = 0; it < NIT; ++it) {
        if constexpr (DEPTH == 1) {
            if (it > 0) STAGE(0, it * 64);
            waitcnt_vm<0>();
        } else if constexpr (DEPTH == 2) {
            if (it + 1 < NIT) { STAGE(buf ^ 1, (it + 1) * 64); waitcnt_vm<NL>(); }
            else              { waitcnt_vm<0>(); }
        } else {  // DEPTH == 3
            if (it + 2 < NIT) {
                int nxt = buf + 2; if (nxt >= 3) nxt -= 3;
                STAGE(nxt, (it + 2) * 64);
                waitcnt_vm<2 * NL>();
            } else if (it + 1 < NIT) { waitcnt_vm<NL>(); }
            else                     { waitcnt_vm<0>(); }
        }
        block_barrier();                 // tile `it` resident for all waves
#pragma unroll
        for (int kk = 0; kk < 2; ++kk) {
            short8 af[FM], bfv[FN];
#pragma unroll
            for (int m = 0; m < FM; ++m) {
                const int row = wr * WMT + m * 16 + lrow;
                af[m] = *(const short8*)&As[buf][row * 64 + (((kk * 4 + kg) ^ (lrow & 7)) << 3)];
            }
#pragma unroll
            for (int n = 0; n < FN; ++n) {
                const int col = wc * WNT + n * 16 + lrow;
                bfv[n] = *(const short8*)&Bs[buf][col * 64 + (((kk * 4 + kg) ^ (lrow & 7)) << 3)];
            }
#pragma unroll
            for (int m = 0; m < FM; ++m)
#pragma unroll
                for (int n = 0; n < FN; ++n)
                    acc[m][n] = __builtin_amdgcn_mfma_f32_16x16x32_bf16(
                        af[m], bfv[n], acc[m][n], 0, 0, 0);
        }
        block_barrier();                 // all reads of buf done before overwrite
        if constexpr (DEPTH == 2) buf ^= 1;
        else if constexpr (DEPTH == 3) { if (++buf == 3) buf = 0; }
    }

    const int lrow4 = (lane >> 4) * 4;
    const int lcol  = lane & 15;
#pragma unroll
    for (int m = 0; m < FM; ++m)
#pragma unroll
        for (int n = 0; n < FN; ++n) {
            const int col = col0 + wc * WNT + n * 16 + lcol;
            const float bv = bias ? bias[col] : 0.f;
            const int row_base = row0 + wr * WMT + m * 16 + lrow4;
            if (VT && col >= 1024) {
                const int vh = (col - 1024) >> 6;
                const int vd = (col - 1024) & 63;
                const int bq = row_base >> 10;
                const int s0 = row_base & 1023;
                union { ushort_t u[4]; uint2 q; } pk;
#pragma unroll
                for (int j = 0; j < 4; ++j) pk.u[j] = f2bf(acc[m][n][j] + bv);
                *(uint2*)(vtg + ((size_t)(bq * 8 + vh) * 64 + vd) * 1024 + s0) = pk.q;
            } else {
#pragma unroll
                for (int j = 0; j < 4; ++j) {
                    const int row = row_base + j;
                    float v = acc[m][n][j] + bv;
                    if (RES)  v += res[(size_t)row * N + col];
                    if (RELU) v = fmaxf(v, 0.f);
                    if (OBF16) ((ushort_t*)out)[(size_t)row * N + col] = f2bf(v);
                    else       ((float*)out)[(size_t)row * N + col] = v;
                }
            }
        }
}

// ---------------------------------------------------------------- attention
// R15 exact: 3-buffer counted-vmcnt prefetch (vmcnt(8) steady state), swapped-
// operand MFMA flash attention, zero-transport P handoff, LDS-staged K/V.
// K swizzle f(row)=(row>>3)&7; V swizzle f(row)=row&7.
__global__ __launch_bounds__(256) void attn_kernel(
    const ushort_t* __restrict__ qkv, const ushort_t* __restrict__ vtg,
    const float* __restrict__ mbias, ushort_t* __restrict__ o)
{
    __shared__ ushort_t Kl[3][64 * 64];   // [key][d]
    __shared__ ushort_t Vl[3][64 * 64];   // [d][key]

    const int t = threadIdx.x, w = t >> 6, l = t & 63;
    const int bid = blockIdx.x;
    const int qt = 15 - (bid >> 5);        // heavy tiles first
    const int bh = bid & 31, b = bh >> 3, h = bh & 7;
    const int q0 = qt * 64;
    const int lg = l >> 4, lr = l & 15;
    const int qi = q0 + w * 16 + lr;       // this lane's query

    const ushort_t* qrow = qkv + (size_t)(b * SS + qi) * 1536 + h * 64;
    const short8 qa0 = *(const short8*)(qrow + lg * 8);
    const short8 qa1 = *(const short8*)(qrow + 32 + lg * 8);

    float m_run = -1e30f, l_run = 0.f;
    f32x4 oacc[4];
#pragma unroll
    for (int nb = 0; nb < 4; ++nb) oacc[nb] = (f32x4){0.f, 0.f, 0.f, 0.f};

    const int krow = 32 * ((lr >> 1) & 1) + 8 * (lr >> 2) + (lr & 1);
    const ushort_t* qkvK = qkv + (size_t)(b * SS) * 1536 + 512 + h * 64;
    const ushort_t* vtgB = vtg + (size_t)bh * 64 * 1024;
    const float*    mb0  = mbias + b * SS + 8 * lg;

    const int sr0 = t >> 3, sc0 = t & 7;

    auto STAGE = [&](int buf, int kt) {
#pragma unroll
        for (int p = 0; p < 2; ++p) {
            const int row = p * 32 + sr0;
            const int ch  = sc0 ^ ((row >> 3) & 7);                 // K swizzle
            gload_lds16(qkvK + (size_t)(kt * 64 + row) * 1536 + ch * 8,
                        (char*)&Kl[buf][0] + (p * 256 + t) * 16);
        }
#pragma unroll
        for (int p = 0; p < 2; ++p) {
            const int row = p * 32 + sr0;
            const int ch  = sc0 ^ (row & 7);                        // V swizzle
            gload_lds16(vtgB + (size_t)row * 1024 + kt * 64 + ch * 8,
                        (char*)&Vl[buf][0] + (p * 256 + t) * 16);
        }
    };

    auto COMPUTE = [&](int buf, int kt) {
        const ushort_t* Kb = &Kl[buf][0];
        const ushort_t* Vb = &Vl[buf][0];
        short8 kf[8], vf[8];
#pragma unroll
        for (int nf = 0; nf < 4; ++nf) {
            const int row = 2 * nf + krow;
            const int sw  = (row >> 3) & 7;
            kf[2 * nf]     = *(const short8*)&Kb[row * 64 + ((lg ^ sw) << 3)];
            kf[2 * nf + 1] = *(const short8*)&Kb[row * 64 + (((4 + lg) ^ sw) << 3)];
        }
#pragma unroll
        for (int nb = 0; nb < 4; ++nb) {
            const int row = 16 * nb + lr;
            const int sw  = row & 7;
            vf[2 * nb]     = *(const short8*)&Vb[row * 64 + ((lg ^ sw) << 3)];
            vf[2 * nb + 1] = *(const short8*)&Vb[row * 64 + (((4 + lg) ^ sw) << 3)];
        }
        const float* mrow = mb0 + kt * 64;
        const float4 mA = *(const float4*)(mrow);
        const float4 mB = *(const float4*)(mrow + 4);
        const float4 mC = *(const float4*)(mrow + 32);
        const float4 mD = *(const float4*)(mrow + 36);
        // S = K * Q^T
        f32x4 s[4];
#pragma unroll
        for (int nf = 0; nf < 4; ++nf) {
            f32x4 a = (f32x4){0.f, 0.f, 0.f, 0.f};
            a = __builtin_amdgcn_mfma_f32_16x16x32_bf16(kf[2 * nf],     qa0, a, 0, 0, 0);
            a = __builtin_amdgcn_mfma_f32_16x16x32_bf16(kf[2 * nf + 1], qa1, a, 0, 0, 0);
            s[nf] = a;
        }
        const bool diag = (kt == qt);
        const int kbase = kt * 64 + 8 * lg;
#pragma unroll
        for (int nf = 0; nf < 4; ++nf) {
#pragma unroll
            for (int r = 0; r < 4; ++r) {
                const int e = r & 1, oo = (r >> 1) & 1;
                const int idx = 2 * nf + e;              // 0..7
                const float bias = oo ? (idx < 4 ? ((const float*)&mC)[idx] : ((const float*)&mD)[idx - 4])
                                      : (idx < 4 ? ((const float*)&mA)[idx] : ((const float*)&mB)[idx - 4]);
                float sv = s[nf][r] * 0.125f + bias;
                if (diag && (kbase + idx + 32 * oo) > qi) sv = -1e9f;
                s[nf][r] = sv;
            }
        }
        float pm[4];
#pragma unroll
        for (int nf = 0; nf < 4; ++nf)
            pm[nf] = fmaxf(fmaxf(s[nf][0], s[nf][1]), fmaxf(s[nf][2], s[nf][3]));
        float mx = fmaxf(fmaxf(pm[0], pm[1]), fmaxf(pm[2], pm[3]));
        mx = fmaxf(mx, __shfl_xor(mx, 16));
        mx = fmaxf(mx, __shfl_xor(mx, 32));
        const float mnew = fmaxf(m_run, mx);
        const float rs   = __expf(m_run - mnew);
        m_run = mnew;
        float ps[4];
#pragma unroll
        for (int nf = 0; nf < 4; ++nf) {
#pragma unroll
            for (int r = 0; r < 4; ++r) s[nf][r] = __expf(s[nf][r] - mnew);
            ps[nf] = (s[nf][0] + s[nf][1]) + (s[nf][2] + s[nf][3]);
        }
        float tsum = (ps[0] + ps[1]) + (ps[2] + ps[3]);
        tsum += __shfl_xor(tsum, 16);
        tsum += __shfl_xor(tsum, 32);
        l_run = l_run * rs + tsum;
#pragma unroll
        for (int nb = 0; nb < 4; ++nb)
#pragma unroll
            for (int r = 0; r < 4; ++r) oacc[nb][r] *= rs;
        union { unsigned u[4]; short8 s8; } pa0u, pa1u;
#pragma unroll
        for (int nf = 0; nf < 4; ++nf) {
            pa0u.u[nf] = ((unsigned)f2bf(s[nf][1]) << 16) | (unsigned)f2bf(s[nf][0]);
            pa1u.u[nf] = ((unsigned)f2bf(s[nf][3]) << 16) | (unsigned)f2bf(s[nf][2]);
        }
#pragma unroll
        for (int nb = 0; nb < 4; ++nb) {
            oacc[nb] = __builtin_amdgcn_mfma_f32_16x16x32_bf16(vf[2 * nb],     pa0u.s8, oacc[nb], 0, 0, 0);
            oacc[nb] = __builtin_amdgcn_mfma_f32_16x16x32_bf16(vf[2 * nb + 1], pa1u.s8, oacc[nb], 0, 0, 0);
        }
    };

    // 3-deep prefetch pipeline
    STAGE(0, 0);
    if (qt >= 1) STAGE(1, 1);
    int buf = 0;
    for (int kt = 0; kt <= qt; ++kt) {
        if (kt + 2 <= qt) {
            int nxt = buf + 2; if (nxt >= 3) nxt -= 3;
            STAGE(nxt, kt + 2);
            asm volatile("s_waitcnt vmcnt(8)" ::: "memory");   // await tile kt only
        } else if (kt + 1 <= qt) {
            asm volatile("s_waitcnt vmcnt(4)" ::: "memory");
        } else {
            asm volatile("s_waitcnt vmcnt(0)" ::: "memory");
        }
        block_barrier();                 // tile kt resident for all waves
        COMPUTE(buf, kt);
        block_barrier();                 // all reads of buf done before overwrite
        if (++buf == 3) buf = 0;
    }

    const float inv = 1.0f / l_run;
    ushort_t* orow = o + (size_t)(b * SS + qi) * 512 + h * 64;
#pragma unroll
    for (int nb = 0; nb < 4; ++nb) {
        union { ushort_t u[4]; uint2 q; } pk;
#pragma unroll
        for (int r = 0; r < 4; ++r) pk.u[r] = f2bf(oacc[nb][r] * inv);
        *(uint2*)(orow + nb * 16 + 4 * lg) = pk.q;
    }
}

// ---------------------------------------------------------------- launch
extern "C" void kernel_launch(void* const* d_in, const int* in_sizes, int n_in,
                              void* d_out, int out_size, void* d_ws, size_t ws_size,
                              hipStream_t stream)
{
    const int*   ids   = (const int*)d_in[0];
    const int*   am    = (const int*)d_in[1];
    const float* emb   = (const float*)d_in[2];
    const float* wq    = (const float*)d_in[3];
    const float* bq    = (const float*)d_in[4];
    const float* wk    = (const float*)d_in[5];
    const float* bk    = (const float*)d_in[6];
    const float* wv    = (const float*)d_in[7];
    const float* bv    = (const float*)d_in[8];
    const float* wo    = (const float*)d_in[9];
    const float* bo    = (const float*)d_in[10];
    const float* ln1g  = (const float*)d_in[11];
    const float* ln1b  = (const float*)d_in[12];
    const float* w1    = (const float*)d_in[13];
    const float* b1    = (const float*)d_in[14];
    const float* w2    = (const float*)d_in[15];
    const float* b2    = (const float*)d_in[16];
    const float* ln2g  = (const float*)d_in[17];
    const float* ln2b  = (const float*)d_in[18];
    const float* lnfg  = (const float*)d_in[19];
    const float* lnfb  = (const float*)d_in[20];
    const float* lmw   = (const float*)d_in[21];

    char* base = (char*)d_ws;
    float*    h    = (float*)(base);                    //  8 MB
    float*    h2   = (float*)(base + 8388608);          //  8 MB (attn: vtg 4MB)
    ushort_t* hb   = (ushort_t*)(base + 16777216);      //  4 MB
    ushort_t* act  = (ushort_t*)(base + 20971520);      // 16 MB shared
    ushort_t* qkvb = act;                               //   12 MB
    ushort_t* ob   = act + 6291456;                     //    4 MB
    ushort_t* fbuf = act;                               //   16 MB (after attn phase)
    ushort_t* vtg  = (ushort_t*)h2;                     //    4 MB, attn-phase only

    // weight-conversion scratch: one-shot if ws allows, else per-layer rotate
    const bool onep = ws_size >= (size_t)76100000;
    ushort_t* wl   = (ushort_t*)(base + 37748736);      // path A: 36 MB, path B: 6.3 MB
    float*    bqkv; ushort_t* lmwb; float* mbias;
    if (onep) {
        bqkv  = (float*)(base + 75497472);               // 36,864 B (6 x 1536)
        lmwb  = (ushort_t*)(base + 75534336);            // 524,288
        mbias = (float*)(base + 76058624);               // 16,384 -> end 76,075,008
    } else {
        bqkv  = (float*)(base + 44040192);
        lmwb  = (ushort_t*)(base + 44046336);
        mbias = (float*)(base + 44570624);
    }

    embed_kernel<<<NROWS, 512, 0, stream>>>(ids, emb, h, hb);
    if (onep) {
        cvt_all<<<18689, 256, 0, stream>>>(wq, wk, wv, wo, w1, w2, bq, bk, bv,
                                           wl, bqkv, lmw, lmwb, am, mbias);
    } else {
        cvt_simple<<<256, 256, 0, stream>>>(lmw, lmwb);
        maskbias_kernel<<<16, 256, 0, stream>>>(am, mbias);
    }

    for (int l = 0; l < NLAYER; ++l) {
        const size_t dd = (size_t)l * 262144;
        const size_t fd = (size_t)l * 1048576;
        ushort_t* lw; const float* lb;
        if (onep) {
            lw = wl + (size_t)l * 3145728;
            lb = bqkv + l * 1536;
        } else {
            cvt_layer<<<3072, 256, 0, stream>>>(wq + dd, wk + dd, wv + dd, wo + dd,
                                                w1 + fd, w2 + fd,
                                                bq + l * 512, bk + l * 512, bv + l * 512,
                                                wl, bqkv);
            lw = wl;
            lb = bqkv;
        }
        // QKV fused GEMM, DEPTH=2 (V written transposed to vtg by epilogue)
        gemm_kernel<64, 128, 2, false, false, true, true><<<dim3(12, 64), 256, 0, stream>>>(
            hb, lw, lb, nullptr, qkvb, vtg, NROWS, 1536, 512);

        attn_kernel<<<512, 256, 0, stream>>>(qkvb, vtg, mbias, ob);

        // narrow GEMMs: 32x64 tile -> grid 1024 = 4 blocks/CU (was 2)
        gemm_kernel<32, 64, 3, false, true, false, false><<<dim3(8, 128), 256, 0, stream>>>(
            ob, lw + 786432, bo + l * 512, h, h2, nullptr, NROWS, 512, 512);
        ln_kernel<<<NROWS, 512, 0, stream>>>(h2, ln1g + l * 512, ln1b + l * 512, h, hb);

        gemm_kernel<64, 128, 1, true, false, true, false><<<dim3(16, 64), 256, 0, stream>>>(
            hb, lw + 1048576, b1 + l * 2048, nullptr, fbuf, nullptr, NROWS, 2048, 512);
        gemm_kernel<32, 64, 3, false, true, false, false><<<dim3(8, 128), 256, 0, stream>>>(
            fbuf, lw + 2097152, b2 + l * 512, h, h2, nullptr, NROWS, 512, 2048);
        ln_kernel<<<NROWS, 512, 0, stream>>>(h2, ln2g + l * 512, ln2b + l * 512, h, hb);
    }

    ln_kernel<<<NROWS, 512, 0, stream>>>(h, lnfg, lnfb, h, hb);
    gemm_kernel<32, 64, 3, false, false, false, false><<<dim3(8, 128), 256, 0, stream>>>(
        hb, lmwb, nullptr, nullptr, d_out, nullptr, NROWS, 512, 512);
}